// Round 14
// baseline (1579.361 us; speedup 1.0000x reference)
//
#include <hip/hip_runtime.h>
#include <cstdio>
#include <cstdint>

// Problem constants: N=8192 tokens, D=256, A=1024, K=65 edge types, E=4096 edges.
#define NTOK 8192
#define DIM  256
#define AA   1024
#define KE   65
#define EE   4096

typedef unsigned short u16;
typedef __attribute__((ext_vector_type(4))) float   f32x4;
typedef __attribute__((ext_vector_type(8))) short   bf16x8;
typedef __attribute__((ext_vector_type(8))) unsigned short u16x8;

#define DEVI __device__ __forceinline__

DEVI u16 f2bf(float f) {               // RNE f32 -> bf16 bits
  union { float f; unsigned u; } x; x.f = f;
  unsigned r = x.u + 0x7FFFu + ((x.u >> 16) & 1u);
  return (u16)(r >> 16);
}
DEVI float bf2f(u16 h) {
  union { unsigned u; float f; } x; x.u = ((unsigned)h) << 16;
  return x.f;
}

DEVI void gload16(const void* g, void* l) {
  __builtin_amdgcn_global_load_lds(
      (const __attribute__((address_space(1))) void*)g,
      (__attribute__((address_space(3))) void*)l,
      16, 0, 0);
}

DEVI void barx() {
  asm volatile("" ::: "memory");
  __builtin_amdgcn_s_barrier();
  asm volatile("" ::: "memory");
}

// Stage one 128x64 bf16 half-tile global->LDS, 512-thread block (2 gloads/thr).
// Swizzle (BK=64, 128B rows): physical o holds logical q = o ^ (((o>>7)&7)<<4).
DEVI void stage_half(const u16* __restrict__ g0, int ld, char* dst, int tid) {
#pragma unroll
  for (int rr = 0; rr < 2; ++rr) {
    int o = rr * 8192 + (tid >> 6) * 1024 + (tid & 63) * 16;
    int q = o ^ (((o >> 7) & 7) << 4);
    gload16(g0 + (size_t)(q >> 7) * ld + ((q & 127) >> 1),
            dst + rr * 8192 + (tid >> 6) * 1024);
  }
}

// Stage one 128x32 bf16 tile (8KB), 256-thread block (2 gloads/thr).
// Swizzle (BK=32, 64B rows): physical o holds logical q = o ^ (((o>>7)&3)<<4).
DEVI void stage_t32(const u16* __restrict__ g0, int ld, char* dst, int tid) {
#pragma unroll
  for (int rr = 0; rr < 2; ++rr) {
    int o = rr * 4096 + tid * 16;
    int q = o ^ (((o >> 7) & 3) << 4);
    gload16(g0 + (size_t)(q >> 6) * ld + ((q & 63) >> 1),
            dst + rr * 4096 + (tid >> 6) * 1024);
  }
}

// ---------------------------------------------------------------------------
// gemm4t: 128x128-tile bf16 GEMM, C = A @ B^T, 256 threads (4 waves, 2x2),
// BK=32 TRIPLE-buffered LDS (48KB) -> 3 blocks/CU, ~2.5 K-tiles of slack.
// Queue mapping (QMODE 1): XCD owns an NT-slice; nt-OUTER, mt-FASTEST over
// the FULL MT (no super-rows): each B panel is staged ONCE per XCD (B-HBM
// traffic = compulsory minimum); A (small, 8.4MB) stays L3-hot throughout.
// EPI 1: o_s[row*ldc+col] = bf16(acc*scale)
// EPI 2: out[e,k] += sum_d acc*Hu  (atomicAdd)
// ---------------------------------------------------------------------------
template<int EPI, int QMODE>
__global__ __launch_bounds__(256, 3)
void gemm4t(const u16* __restrict__ A, int lda,
            const u16* __restrict__ B, int ldb,
            int MT, int NT, int K,
            u16* __restrict__ o_s, float scale, int ldc,
            const u16* __restrict__ Hu, float* __restrict__ o_e,
            int* __restrict__ qcnt)
{
  __shared__ __align__(16) char lds[49152];
  __shared__ int s_idx;
  char* ldsA = lds;              // 3 x 8KB
  char* ldsB = lds + 24576;      // 3 x 8KB

  const int tid = threadIdx.x, lane = tid & 63, wave = tid >> 6;
  const int wm = (wave >> 1) * 64, wn = (wave & 1) * 64;
  const int KT = K >> 5;
  const int r15 = lane & 15, g16b = (lane >> 4) * 16;   // byte K-offset

  int xcc;
  asm volatile("s_getreg_b32 %0, hwreg(20, 0, 32)" : "=s"(xcc));  // HW_REG_XCC_ID
  xcc &= 7;
  const int MPX = MT >> 3;
  const int NQ = NT >> 3, NR = NT & 7;

  for (int dx = 0; dx < 8; ++dx) {
    const int qi = (xcc + dx) & 7;
    int per, ntb = 0, ntc = 0;
    if constexpr (QMODE == 0) {
      per = (MT * NT) >> 3;
    } else {
      ntc = NQ + (qi < NR ? 1 : 0);
      ntb = qi * NQ + (qi < NR ? qi : NR);
      per = ntc * MT;
    }
    while (true) {
      if (tid == 0) s_idx = atomicAdd(&qcnt[qi], 1);
      __syncthreads();
      const int idx = s_idx;
      __syncthreads();
      if (idx >= per) break;
      int mt, nt;
      if constexpr (QMODE == 0) {
        mt = qi * MPX + (idx % MPX); nt = idx / MPX;
      } else {
        mt = idx % MT;               // mt fastest over FULL MT
        nt = ntb + idx / MT;         // B panel staged once per XCD
      }
      const int m0 = mt * 128, n0 = nt * 128;
      const u16* Ag = A + (size_t)m0 * lda;
      const u16* Bg = B + (size_t)n0 * ldb;

      f32x4 acc[4][4];
#pragma unroll
      for (int m = 0; m < 4; ++m)
#pragma unroll
        for (int n = 0; n < 4; ++n) acc[m][n] = f32x4{0.f, 0.f, 0.f, 0.f};

      // prologue: stage t0,t1,t2 (12 gloads); vmcnt(8) => t0 landed
      stage_t32(Ag,      lda, ldsA,         tid);
      stage_t32(Bg,      ldb, ldsB,         tid);
      stage_t32(Ag + 32, lda, ldsA + 8192,  tid);
      stage_t32(Bg + 32, ldb, ldsB + 8192,  tid);
      stage_t32(Ag + 64, lda, ldsA + 16384, tid);
      stage_t32(Bg + 64, ldb, ldsB + 16384, tid);
      asm volatile("s_waitcnt vmcnt(8)" ::: "memory");
      barx();

      int bi = 0;                      // t % 3, maintained incrementally
      for (int t = 0; t < KT; ++t) {
        const char* Ab = ldsA + bi * 8192;
        const char* Bb = ldsB + bi * 8192;
        bf16x8 a[4], b[4];
#pragma unroll
        for (int m = 0; m < 4; ++m) {
          int p = (wm + m * 16 + r15) * 64 + g16b;
          p ^= ((p >> 7) & 3) << 4;
          a[m] = *(const bf16x8*)(Ab + p);
        }
#pragma unroll
        for (int n = 0; n < 4; ++n) {
          int p = (wn + n * 16 + r15) * 64 + g16b;
          p ^= ((p >> 7) & 3) << 4;
          b[n] = *(const bf16x8*)(Bb + p);
        }
        asm volatile("s_waitcnt lgkmcnt(0)" ::: "memory");
        __builtin_amdgcn_sched_barrier(0);
        barx();                        // all waves' reads of buf bi done
        if (t + 3 < KT) {              // stage t+3 into buf bi (WAR-safe)
          stage_t32(Ag + (size_t)(t + 3) * 32, lda, ldsA + bi * 8192, tid);
          stage_t32(Bg + (size_t)(t + 3) * 32, ldb, ldsB + bi * 8192, tid);
        }
        __builtin_amdgcn_s_setprio(1);
#pragma unroll
        for (int m = 0; m < 4; ++m)
#pragma unroll
          for (int n = 0; n < 4; ++n)
            acc[m][n] = __builtin_amdgcn_mfma_f32_16x16x32_bf16(
                a[m], b[n], acc[m][n], 0, 0, 0);
        __builtin_amdgcn_s_setprio(0);
        // drain exactly tile t+1 (uniform tail ledger: 12 -> 8/4/0 in flight)
        if (t + 3 < KT)      asm volatile("s_waitcnt vmcnt(8)" ::: "memory");
        else if (t + 2 < KT) asm volatile("s_waitcnt vmcnt(4)" ::: "memory");
        else                 asm volatile("s_waitcnt vmcnt(0)" ::: "memory");
        barx();                        // tile t+1 fully in LDS for all waves
        bi = (bi == 2) ? 0 : bi + 1;
      }

      // ---- epilogue ----
      const int rgrp = lane >> 4, cid = lane & 15;
      if constexpr (EPI == 1) {
#pragma unroll
        for (int m = 0; m < 4; ++m)
#pragma unroll
          for (int n = 0; n < 4; ++n)
#pragma unroll
            for (int j = 0; j < 4; ++j) {
              int row = m0 + wm + m * 16 + rgrp * 4 + j;
              int col = n0 + wn + n * 16 + cid;
              o_s[(size_t)row * ldc + col] = f2bf(acc[m][n][j] * scale);
            }
      } else {
        const int kidx  = n0 >> 10;          // 128-tile stays within one k
        const int dbase = (n0 & 1023) + wn;
#pragma unroll
        for (int m = 0; m < 4; ++m)
#pragma unroll
          for (int j = 0; j < 4; ++j) {
            int row = m0 + wm + m * 16 + rgrp * 4 + j;
            float p = 0.f;
#pragma unroll
            for (int n = 0; n < 4; ++n)
              p += acc[m][n][j] * bf2f(Hu[(size_t)row * AA + dbase + n * 16 + cid]);
            p += __shfl_xor(p, 1, 64);
            p += __shfl_xor(p, 2, 64);
            p += __shfl_xor(p, 4, 64);
            p += __shfl_xor(p, 8, 64);
            if (cid == 0) atomicAdd(&o_e[(size_t)row * KE + kidx], p);
          }
      }
    }
  }
}

// ---------------------------------------------------------------------------
// gemm8: persistent 256x256-tile bf16 GEMM (8 waves, 1 block/CU), continuous
// m201-style 8-phase pipeline + per-XCD queues (nt-outer, mt-fastest).
// Used for the scores GEMM.
// ---------------------------------------------------------------------------
template<int EPI, int QMODE>
__global__ __launch_bounds__(512, 2)
void gemm8(const u16* __restrict__ A, int lda,
           const u16* __restrict__ B, int ldb,
           int MT, int NT, int K,
           u16* __restrict__ o_s, float scale, int ldc,
           const u16* __restrict__ Hu, float* __restrict__ o_e,
           int* __restrict__ qcnt)
{
  __shared__ __align__(16) char lds[131072];
  __shared__ int s_next[3];    // {m0, n0, have}
  char* ldsA = lds;            // [parity 32KB][half 16KB]
  char* ldsB = lds + 65536;

  const int tid = threadIdx.x, lane = tid & 63, wave = tid >> 6;
  const int wm = (wave >> 2) * 128;
  const int wn = (wave & 3) * 64;
  const int wnl = (wave & 1) * 64;
  const int KT = K >> 6, KT2 = KT >> 1;
  const int r15 = lane & 15, g16 = (lane >> 4) << 4;

  int xcc;
  asm volatile("s_getreg_b32 %0, hwreg(20, 0, 32)" : "=s"(xcc));  // HW_REG_XCC_ID
  xcc &= 7;
  const int MPX = MT >> 3;
  const int NQ = NT >> 3, NR = NT & 7;

  const char* Ab_e = ldsA +         (wm >> 7) * 16384;
  const char* Ab_o = ldsA + 32768 + (wm >> 7) * 16384;
  const char* Bb_e = ldsB +         (wn >> 7) * 16384;
  const char* Bb_o = ldsB + 32768 + (wn >> 7) * 16384;

  int dxr = 0;
  auto pop_next = [&]() {
    while (dxr < 8) {
      const int qi = (xcc + dxr) & 7;
      int per, ntb = 0, ntc = 0;
      if constexpr (QMODE == 0) {
        per = (MT * NT) >> 3;
      } else {
        ntc = NQ + (qi < NR ? 1 : 0);
        ntb = qi * NQ + (qi < NR ? qi : NR);
        per = ntc * MT;
      }
      const int idx = atomicAdd(&qcnt[qi], 1);
      if (idx < per) {
        int mt, nt;
        if constexpr (QMODE == 0) {
          mt = qi * MPX + (idx % MPX); nt = idx / MPX;
        } else {
          mt = idx % MT;             // mt fastest over FULL MT
          nt = ntb + idx / MT;       // B panel staged once per XCD
        }
        s_next[0] = mt * 256; s_next[1] = nt * 256; s_next[2] = 1;
        return;
      }
      ++dxr;
    }
    s_next[2] = 0;
  };

  if (tid == 0) pop_next();
  __syncthreads();
  int m0 = s_next[0], n0 = s_next[1];
  if (!s_next[2]) return;

#define STAGE_A2(tk, h) do { const int _tk = (tk); \
    if (_tk < KT) stage_half(A + (size_t)(m0 + (h)*128) * lda + (size_t)_tk*64, lda, \
                             ldsA + (_tk & 1) * 32768 + (h) * 16384, tid); \
    else if (have_n) stage_half(A + (size_t)(m0n + (h)*128) * lda + (size_t)(_tk-KT)*64, lda, \
                                ldsA + (_tk & 1) * 32768 + (h) * 16384, tid); } while (0)
#define STAGE_B2(tk, h) do { const int _tk = (tk); \
    if (_tk < KT) stage_half(B + (size_t)(n0 + (h)*128) * ldb + (size_t)_tk*64, ldb, \
                             ldsB + (_tk & 1) * 32768 + (h) * 16384, tid); \
    else if (have_n) stage_half(B + (size_t)(n0n + (h)*128) * ldb + (size_t)(_tk-KT)*64, ldb, \
                                ldsB + (_tk & 1) * 32768 + (h) * 16384, tid); } while (0)
#define RD_A4(base, q) \
  _Pragma("unroll") for (int m = (q)*4; m < (q)*4+4; ++m) \
  _Pragma("unroll") for (int kk = 0; kk < 2; ++kk) { \
    int p = (m*16 + r15)*128 + kk*64 + g16; p ^= ((p>>7)&7)<<4; \
    a[m][kk] = *(const bf16x8*)((base) + p); }
#define RD_B2(base, q) \
  _Pragma("unroll") for (int n = (q)*2; n < (q)*2+2; ++n) \
  _Pragma("unroll") for (int kk = 0; kk < 2; ++kk) { \
    int p = (wnl + n*16 + r15)*128 + kk*64 + g16; p ^= ((p>>7)&7)<<4; \
    b[n][kk] = *(const bf16x8*)((base) + p); }
#define MM(QM, QN) do { \
  __builtin_amdgcn_s_setprio(1); \
  _Pragma("unroll") for (int kk = 0; kk < 2; ++kk) \
  _Pragma("unroll") for (int m = 0; m < 4; ++m) \
  _Pragma("unroll") for (int n = 0; n < 2; ++n) \
    acc[(QM)*4+m][(QN)*2+n] = __builtin_amdgcn_mfma_f32_16x16x32_bf16( \
        a[(QM)*4+m][kk], b[(QN)*2+n][kk], acc[(QM)*4+m][(QN)*2+n], 0, 0, 0); \
  __builtin_amdgcn_s_setprio(0); } while (0)
#define WAIT_LGKM0 do { asm volatile("s_waitcnt lgkmcnt(0)" ::: "memory"); \
                        __builtin_amdgcn_sched_barrier(0); } while (0)
#define KTILE(t, AB, BB) do { \
    RD_B2(BB, 0); RD_A4(AB, 0); \
    STAGE_B2((t) + 1, 1); \
    asm volatile("s_waitcnt lgkmcnt(8)" ::: "memory"); \
    barx(); WAIT_LGKM0; \
    MM(0, 0); \
    barx(); \
    RD_B2(BB, 1); \
    barx(); WAIT_LGKM0; \
    MM(0, 1); \
    barx(); \
    RD_A4(AB, 1); \
    STAGE_B2((t) + 2, 0); \
    barx(); WAIT_LGKM0; \
    MM(1, 1); \
    barx(); \
    STAGE_A2((t) + 2, 0); \
    STAGE_A2((t) + 2, 1); \
    barx(); \
    __builtin_amdgcn_sched_barrier(0); \
    MM(1, 0); \
    if (vm6) asm volatile("s_waitcnt vmcnt(6)" ::: "memory"); \
    else     asm volatile("s_waitcnt vmcnt(0)" ::: "memory"); \
    barx(); } while (0)

  {
    const int m0n = 0, n0n = 0; const bool have_n = false; (void)m0n; (void)n0n; (void)have_n;
    STAGE_A2(0, 0); STAGE_A2(0, 1); STAGE_B2(0, 0); STAGE_B2(0, 1);
    STAGE_B2(1, 0); STAGE_A2(1, 0); STAGE_A2(1, 1);
  }
  asm volatile("s_waitcnt vmcnt(6)" ::: "memory");
  barx();

  while (true) {
    f32x4 acc[8][4];
#pragma unroll
    for (int m = 0; m < 8; ++m)
#pragma unroll
      for (int n = 0; n < 4; ++n) acc[m][n] = f32x4{0.f, 0.f, 0.f, 0.f};

    int m0n = 0, n0n = 0;
    bool have_n = false;

    for (int i = 0; i < KT2; ++i) {
      const int ta = 2 * i, tb = 2 * i + 1;
      if (i == KT2 - 2 && tid == 0) pop_next();
      if (i == KT2 - 1) { m0n = s_next[0]; n0n = s_next[1]; have_n = (s_next[2] != 0); }
      const bool tail = (i == KT2 - 1);
      const bool vm6 = !tail || have_n;
      bf16x8 a[8][2], b[4][2];
      KTILE(ta, Ab_e, Bb_e);
      KTILE(tb, Ab_o, Bb_o);
    }

    const int rgrp = lane >> 4, cid = lane & 15;
    if constexpr (EPI == 1) {
#pragma unroll
      for (int m = 0; m < 8; ++m)
#pragma unroll
        for (int n = 0; n < 4; ++n)
#pragma unroll
          for (int j = 0; j < 4; ++j) {
            int row = m0 + wm + m * 16 + rgrp * 4 + j;
            int col = n0 + wn + n * 16 + cid;
            o_s[(size_t)row * ldc + col] = f2bf(acc[m][n][j] * scale);
          }
    } else {
      const int kidx  = n0 >> 10;
      const int dbase = (n0 & 1023) + wn;
#pragma unroll
      for (int m = 0; m < 8; ++m)
#pragma unroll
        for (int j = 0; j < 4; ++j) {
          int row = m0 + wm + m * 16 + rgrp * 4 + j;
          float p = 0.f;
#pragma unroll
          for (int n = 0; n < 4; ++n)
            p += acc[m][n][j] * bf2f(Hu[(size_t)row * AA + dbase + n * 16 + cid]);
          p += __shfl_xor(p, 1, 64);
          p += __shfl_xor(p, 2, 64);
          p += __shfl_xor(p, 4, 64);
          p += __shfl_xor(p, 8, 64);
          if (cid == 0) atomicAdd(&o_e[(size_t)row * KE + kidx], p);
        }
    }

    if (!have_n) break;
    m0 = m0n; n0 = n0n;
  }
#undef STAGE_A2
#undef STAGE_B2
#undef RD_A4
#undef RD_B2
#undef MM
#undef WAIT_LGKM0
#undef KTILE
}

// ---------------------------------------------------------------------------
// Generic 128x128-tile bf16 GEMM, C = A @ B^T (2-phase; QKV / PV / fallbacks)
// ---------------------------------------------------------------------------
#define BM 128
#define BN 128
#define BK 64

template<int EPI, bool BF32>
__global__ __launch_bounds__(256)
void gemm_bt(const u16* __restrict__ A, int lda,
             const void* __restrict__ Bptr, int ldb,
             int MT, int NT, int K,
             u16* __restrict__ o_q, u16* __restrict__ o_k, u16* __restrict__ o_vt,
             const float* __restrict__ biasc,
             u16* __restrict__ o_s, float scale, int ldc,
             const u16* __restrict__ Hu, float* __restrict__ o_e)
{
  const int nb  = MT * NT;
  const int per = nb >> 3;                    // grids are multiples of 8
  int bid = blockIdx.x;
  bid = (bid & 7) * per + (bid >> 3);         // XCD-contiguous chunks
  const int mt = bid % MT, nt = bid / MT;     // mt fast => B panel L2 reuse
  const int m0 = mt * BM, n0 = nt * BN;

  __shared__ u16 As[BM * BK];
  __shared__ u16 Bs[BN * BK];

  const int tid  = threadIdx.x;
  const int lane = tid & 63, wave = tid >> 6;
  const int wm = (wave >> 1) * 64, wn = (wave & 1) * 64;

  f32x4 acc[4][4];
#pragma unroll
  for (int m = 0; m < 4; ++m)
#pragma unroll
    for (int n = 0; n < 4; ++n) acc[m][n] = f32x4{0.f, 0.f, 0.f, 0.f};

  const u16*   Bh = (const u16*)Bptr;
  const float* Bf = (const float*)Bptr;

  const int KT = K / BK;
  for (int kt = 0; kt < KT; ++kt) {
    const int k0 = kt * BK;
#pragma unroll
    for (int it = 0; it < 4; ++it) {
      int o = it * 4096 + wave * 1024 + lane * 16;
      int r = o >> 7;
      int c = (o & 127) >> 1;
      gload16(A + (size_t)(m0 + r) * lda + k0 + c,
              &As[(it * 4096 + wave * 1024) >> 1]);
    }
    if constexpr (!BF32) {
#pragma unroll
      for (int it = 0; it < 4; ++it) {
        int o = it * 4096 + wave * 1024 + lane * 16;
        int r = o >> 7;
        int c = (o & 127) >> 1;
        gload16(Bh + (size_t)(n0 + r) * ldb + k0 + c,
                &Bs[(it * 4096 + wave * 1024) >> 1]);
      }
    } else {
#pragma unroll
      for (int it = 0; it < 8; ++it) {
        int e = it * 1024 + tid * 4;
        int r = e >> 6, c = e & 63;
        const float4 v = *(const float4*)(Bf + (size_t)(n0 + r) * ldb + k0 + c);
        ushort4 h;
        h.x = f2bf(v.x); h.y = f2bf(v.y); h.z = f2bf(v.z); h.w = f2bf(v.w);
        *(ushort4*)&Bs[r * BK + c] = h;
      }
    }
    asm volatile("s_waitcnt vmcnt(0)" ::: "memory");
    __syncthreads();

#pragma unroll
    for (int kk = 0; kk < 2; ++kk) {
      const int ro = lane & 15;
      const int ko = kk * 32 + (lane >> 4) * 8;
      bf16x8 af[4], bfg[4];
#pragma unroll
      for (int m = 0; m < 4; ++m)
        af[m] = *(const bf16x8*)&As[(wm + m * 16 + ro) * BK + ko];
#pragma unroll
      for (int n = 0; n < 4; ++n)
        bfg[n] = *(const bf16x8*)&Bs[(wn + n * 16 + ro) * BK + ko];
#pragma unroll
      for (int m = 0; m < 4; ++m)
#pragma unroll
        for (int n = 0; n < 4; ++n)
          acc[m][n] = __builtin_amdgcn_mfma_f32_16x16x32_bf16(
              af[m], bfg[n], acc[m][n], 0, 0, 0);
    }
    __syncthreads();
  }

  const int rgrp = lane >> 4, cid = lane & 15;

  if constexpr (EPI == 0) {
#pragma unroll
    for (int m = 0; m < 4; ++m)
#pragma unroll
      for (int n = 0; n < 4; ++n)
#pragma unroll
        for (int j = 0; j < 4; ++j) {
          int row = m0 + wm + m * 16 + rgrp * 4 + j;
          int col = n0 + wn + n * 16 + cid;
          float v = acc[m][n][j] + biasc[col];
          u16 h = f2bf(v);
          if (col < 1024)       o_q[(size_t)row * AA + col] = h;
          else if (col < 2048)  o_k[(size_t)row * AA + (col - 1024)] = h;
          else                  o_vt[(size_t)(col - 2048) * NTOK + row] = h;
        }
  } else if constexpr (EPI == 1) {
#pragma unroll
    for (int m = 0; m < 4; ++m)
#pragma unroll
      for (int n = 0; n < 4; ++n)
#pragma unroll
        for (int j = 0; j < 4; ++j) {
          int row = m0 + wm + m * 16 + rgrp * 4 + j;
          int col = n0 + wn + n * 16 + cid;
          o_s[(size_t)row * ldc + col] = f2bf(acc[m][n][j] * scale);
        }
  } else {
    const int kidx  = n0 >> 10;
    const int dbase = (n0 & 1023) + wn;
#pragma unroll
    for (int m = 0; m < 4; ++m)
#pragma unroll
      for (int j = 0; j < 4; ++j) {
        int row = m0 + wm + m * 16 + rgrp * 4 + j;
        float p = 0.f;
#pragma unroll
        for (int n = 0; n < 4; ++n) {
          int d = dbase + n * 16 + cid;
          p += acc[m][n][j] * bf2f(Hu[(size_t)row * AA + d]);
        }
        p += __shfl_xor(p, 1, 64);
        p += __shfl_xor(p, 2, 64);
        p += __shfl_xor(p, 4, 64);
        p += __shfl_xor(p, 8, 64);
        if (cid == 0) atomicAdd(&o_e[(size_t)row * KE + kidx], p);
      }
  }
}

// ---------------------------------------------------------------------------
// Row softmax over 8192 bf16 columns, in place. One block per row.
// ---------------------------------------------------------------------------
__global__ __launch_bounds__(256)
void softmax_rows(u16* __restrict__ S)
{
  const size_t base = (size_t)blockIdx.x * 8192;
  const int tid = threadIdx.x;
  const int lane = tid & 63, wave = tid >> 6;
  float v[32];
#pragma unroll
  for (int c = 0; c < 4; ++c) {
    u16x8 u = *(const u16x8*)&S[base + c * 2048 + tid * 8];
#pragma unroll
    for (int j = 0; j < 8; ++j) v[c * 8 + j] = bf2f(u[j]);
  }
  float mx = -1e30f;
#pragma unroll
  for (int i = 0; i < 32; ++i) mx = fmaxf(mx, v[i]);
#pragma unroll
  for (int off = 1; off < 64; off <<= 1) mx = fmaxf(mx, __shfl_xor(mx, off, 64));
  __shared__ float r1[4], r2[4];
  if (lane == 0) r1[wave] = mx;
  __syncthreads();
  mx = fmaxf(fmaxf(r1[0], r1[1]), fmaxf(r1[2], r1[3]));

  float s = 0.f;
#pragma unroll
  for (int i = 0; i < 32; ++i) { v[i] = __expf(v[i] - mx); s += v[i]; }
#pragma unroll
  for (int off = 1; off < 64; off <<= 1) s += __shfl_xor(s, off, 64);
  if (lane == 0) r2[wave] = s;
  __syncthreads();
  s = r2[0] + r2[1] + r2[2] + r2[3];
  const float inv = 1.f / s;
#pragma unroll
  for (int c = 0; c < 4; ++c) {
    u16x8 u;
#pragma unroll
    for (int j = 0; j < 8; ++j) u[j] = f2bf(v[c * 8 + j] * inv);
    *(u16x8*)&S[base + c * 2048 + tid * 8] = u;
  }
}

// ---------------------------------------------------------------------------
// Gather Hu/Hv rows from attn_emb. Handles data delivered as int64 OR int32.
// ---------------------------------------------------------------------------
__global__ __launch_bounds__(256)
void gather_rows(const unsigned* __restrict__ dw, const u16* __restrict__ AE,
                 u16* __restrict__ Hu, u16* __restrict__ Hv)
{
  bool i64 = true;
#pragma unroll
  for (int w = 1; w < 32; w += 2) i64 = i64 && (dw[w] == 0u);
  const int e = blockIdx.x;
  const unsigned iu = i64 ? dw[4 * e]     : dw[2 * e];
  const unsigned iv = i64 ? dw[4 * e + 2] : dw[2 * e + 1];
  const int t = threadIdx.x;
  *(ushort4*)&Hu[(size_t)e * AA + t * 4] = *(const ushort4*)&AE[(size_t)iu * AA + t * 4];
  *(ushort4*)&Hv[(size_t)e * AA + t * 4] = *(const ushort4*)&AE[(size_t)iv * AA + t * 4];
}

// zero d_out + build concatenated bias + zero per-XCD work queues
__global__ __launch_bounds__(256)
void init_misc(float* __restrict__ out_e, const float* __restrict__ bq,
               const float* __restrict__ bk, const float* __restrict__ bv,
               float* __restrict__ biasc, int* __restrict__ qall)
{
  const int i = blockIdx.x * 256 + threadIdx.x;
  if (i < EE * KE) out_e[i] = 0.f;
  if (i < 1024) {
    biasc[i]        = bq[i];
    biasc[1024 + i] = bk[i];
    biasc[2048 + i] = bv[i];
  }
  if (i < 64) qall[i] = 0;
}

// grid-stride f32 -> bf16 conversion, float4 granularity
__global__ __launch_bounds__(256)
void cvt_f32_bf16_v4(const float* __restrict__ src, u16* __restrict__ dst, int n4)
{
  for (int i = blockIdx.x * 256 + threadIdx.x; i < n4; i += gridDim.x * 256) {
    float4 v = ((const float4*)src)[i];
    ushort4 h; h.x = f2bf(v.x); h.y = f2bf(v.y); h.z = f2bf(v.z); h.w = f2bf(v.w);
    ((ushort4*)dst)[i] = h;
  }
}

// WqkvT[n][d] = W*(d, n&1023) for n in [0,3072)
__global__ __launch_bounds__(256)
void build_wT(const float* __restrict__ Wq, const float* __restrict__ Wk,
              const float* __restrict__ Wv, u16* __restrict__ WT)
{
  const int nn = blockIdx.x;    // 0..3071
  const int d  = threadIdx.x;   // 0..255
  const float* W = (nn < 1024) ? Wq : ((nn < 2048) ? Wk : Wv);
  WT[nn * DIM + d] = f2bf(W[(size_t)d * AA + (nn & 1023)]);
}

// ---------------------------------------------------------------------------
extern "C" void kernel_launch(void* const* d_in, const int* in_sizes, int n_in,
                              void* d_out, int out_size, void* d_ws, size_t ws_size,
                              hipStream_t stream)
{
  (void)in_sizes; (void)out_size;
  if (n_in < 9) return;
  const float*    emb  = (const float*)d_in[0];
  const unsigned* data = (const unsigned*)d_in[1];
  const float* Wq = (const float*)d_in[2];
  const float* bq = (const float*)d_in[3];
  const float* Wk = (const float*)d_in[4];
  const float* bk = (const float*)d_in[5];
  const float* Wv = (const float*)d_in[6];
  const float* bv = (const float*)d_in[7];
  const float* We = (const float*)d_in[8];
  float* out = (float*)d_out;

  char* ws = (char*)d_ws;
  size_t off = 0;
  auto alloc = [&](size_t bytes) -> void* {
    void* p = ws + off;
    off += (bytes + 255) & ~(size_t)255;
    return p;
  };
  u16*   emb_b = (u16*)alloc((size_t)NTOK * DIM * 2);     //  4.2 MB
  u16*   WT    = (u16*)alloc((size_t)3072 * DIM * 2);     //  1.6 MB
  float* biasc = (float*)alloc(3072 * 4);
  int*   qall  = (int*)alloc(64 * 4);                     // 8 x 8 XCD queues
  u16*   Qb    = (u16*)alloc((size_t)NTOK * AA * 2);      // 16.8 MB
  u16*   Kb    = (u16*)alloc((size_t)NTOK * AA * 2);
  u16*   Vt    = (u16*)alloc((size_t)AA * NTOK * 2);
  u16*   AE    = (u16*)alloc((size_t)NTOK * AA * 2);
  u16*   Hu    = (u16*)alloc((size_t)EE * AA * 2);        //  8.4 MB
  u16*   Hv    = (u16*)alloc((size_t)EE * AA * 2);

  // bf16 copy of W_edge (136 MB) if it fits alongside a score chunk
  const size_t webf_bytes = ((size_t)KE * AA * AA * 2 + 255) & ~(size_t)255;
  u16* We_b = nullptr;
  if (off + webf_bytes + (size_t)1024 * NTOK * 2 <= ws_size) {
    We_b = (u16*)(ws + off);
    off += webf_bytes;
  }

  int chunk = 4096;  // Sc = 64 MB stays L3-resident for softmax + PV
  while (chunk > 128 && off + (size_t)chunk * NTOK * 2 > ws_size) chunk >>= 1;
  u16* Sc = (u16*)alloc((size_t)chunk * NTOK * 2);
  if (off > ws_size) {
    fprintf(stderr, "kernel_launch: ws too small (need %zu, have %zu)\n", off, ws_size);
    return;
  }

  init_misc<<<(EE * KE) / 256, 256, 0, stream>>>(out, bq, bk, bv, biasc, qall);
  cvt_f32_bf16_v4<<<2048, 256, 0, stream>>>(emb, emb_b, NTOK * DIM / 4);
  build_wT<<<3072, 256, 0, stream>>>(Wq, Wk, Wv, WT);
  if (We_b)
    cvt_f32_bf16_v4<<<4096, 256, 0, stream>>>(We, We_b, KE * AA * AA / 4);

  // QKV: (8192,3072,256) on the 128^2 kernel (K too small for the pipelines)
  gemm_bt<0, false><<<64 * 24, 256, 0, stream>>>(
      emb_b, DIM, WT, DIM, 64, 24, DIM,
      Qb, Kb, Vt, biasc, nullptr, 0.f, 0, nullptr, nullptr);

  // attention, Q-chunked
  const int nch = NTOK / chunk;
  for (int ci = 0; ci < nch; ++ci) {
    const u16* Qc = Qb + (size_t)ci * chunk * AA;
    const bool big = ((chunk & 2047) == 0);   // MT multiple of 8
    if (big)
      gemm8<1, 1><<<256, 512, 0, stream>>>(
          Qc, AA, Kb, AA, chunk / 256, 32, AA,
          Sc, 0.0625f, NTOK, nullptr, nullptr, qall + 8 * ci);
    else
      gemm_bt<1, false><<<(chunk / 128) * 64, 256, 0, stream>>>(
          Qc, AA, Kb, AA, chunk / 128, 64, AA,
          nullptr, nullptr, nullptr, nullptr, Sc, 0.0625f, NTOK, nullptr, nullptr);
    softmax_rows<<<chunk, 256, 0, stream>>>(Sc);
    // PV on the 128^2 kernel: (chunk/128)*8 = 256 blocks = full machine
    gemm_bt<1, false><<<(chunk / 128) * 8, 256, 0, stream>>>(
        Sc, NTOK, Vt, NTOK, chunk / 128, 8, NTOK,
        nullptr, nullptr, nullptr, nullptr,
        AE + (size_t)ci * chunk * AA, 1.0f, AA, nullptr, nullptr);
  }

  gather_rows<<<EE, 256, 0, stream>>>(data, AE, Hu, Hv);

  // edge bilinear on gemm4t: nt-outer/mt-fastest => W staged once per XCD
  if (We_b)
    gemm4t<2, 1><<<768, 256, 0, stream>>>(
        Hv, AA, We_b, AA, 32, 520, AA,
        nullptr, 0.f, 0, Hu, out, qall + 32);
  else
    gemm_bt<3, true><<<32 * 520, 256, 0, stream>>>(
        Hv, AA, We, AA, 32, 520, AA,
        nullptr, nullptr, nullptr, nullptr, nullptr, 0.f, 0, Hu, out);
}

// Round 15
// 1496.302 us; speedup vs baseline: 1.0555x; 1.0555x over previous
//
#include <hip/hip_runtime.h>
#include <cstdio>
#include <cstdint>

// Problem constants: N=8192 tokens, D=256, A=1024, K=65 edge types, E=4096 edges.
#define NTOK 8192
#define DIM  256
#define AA   1024
#define KE   65
#define EE   4096

typedef unsigned short u16;
typedef __attribute__((ext_vector_type(4))) float   f32x4;
typedef __attribute__((ext_vector_type(8))) short   bf16x8;
typedef __attribute__((ext_vector_type(8))) unsigned short u16x8;

#define DEVI __device__ __forceinline__

DEVI u16 f2bf(float f) {               // RNE f32 -> bf16 bits
  union { float f; unsigned u; } x; x.f = f;
  unsigned r = x.u + 0x7FFFu + ((x.u >> 16) & 1u);
  return (u16)(r >> 16);
}
DEVI float bf2f(u16 h) {
  union { unsigned u; float f; } x; x.u = ((unsigned)h) << 16;
  return x.f;
}

DEVI void gload16(const void* g, void* l) {
  __builtin_amdgcn_global_load_lds(
      (const __attribute__((address_space(1))) void*)g,
      (__attribute__((address_space(3))) void*)l,
      16, 0, 0);
}

DEVI void barx() {
  asm volatile("" ::: "memory");
  __builtin_amdgcn_s_barrier();
  asm volatile("" ::: "memory");
}

// Stage one 128x64 bf16 half-tile global->LDS, 512-thread block (2 gloads/thr).
// Swizzle (BK=64, 128B rows): physical o holds logical q = o ^ (((o>>7)&7)<<4).
DEVI void stage_half(const u16* __restrict__ g0, int ld, char* dst, int tid) {
#pragma unroll
  for (int rr = 0; rr < 2; ++rr) {
    int o = rr * 8192 + (tid >> 6) * 1024 + (tid & 63) * 16;
    int q = o ^ (((o >> 7) & 7) << 4);
    gload16(g0 + (size_t)(q >> 7) * ld + ((q & 127) >> 1),
            dst + rr * 8192 + (tid >> 6) * 1024);
  }
}

// Stage one 128x32 bf16 tile (8KB), 256-thread block (2 gloads/thr).
// Swizzle (BK=32, 64B rows): physical o holds logical q = o ^ (((o>>7)&3)<<4).
DEVI void stage_t32(const u16* __restrict__ g0, int ld, char* dst, int tid) {
#pragma unroll
  for (int rr = 0; rr < 2; ++rr) {
    int o = rr * 4096 + tid * 16;
    int q = o ^ (((o >> 7) & 3) << 4);
    gload16(g0 + (size_t)(q >> 6) * ld + ((q & 63) >> 1),
            dst + rr * 4096 + (tid >> 6) * 1024);
  }
}

// ---------------------------------------------------------------------------
// gemm4n: 256x128-tile bf16 GEMM, C = A @ B^T, 256 threads = 4 waves (2Mx2N),
// per-wave output 128x64: a[8]+b[4] fragments feed 32 MFMA = 384 B of LDS
// read per MFMA (vs 1024 in the 4x4 shape) -- halves the LDS:MFMA ratio that
// pinned all 128^2 variants at ~28% MfmaUtil.  BK=32, double-buffered 48KB
// LDS -> 2 independent blocks/CU (cross-block latency hiding).
// Per K-tile t: 12 ds_reads -> lgkm0 -> bar -> stage t+2 (6 gloads, WAR-safe)
// -> 32 MFMA -> vmcnt(6) (drains exactly t+1) -> bar.
// Per-XCD queues: nt-slice, super-rows of 8 mt (B panel shared by 16 blocks,
// A super-slice L2-resident).  REQUIRES KT >= 2, MT multiple of 8.
// EPI 1: o_s[row*ldc+col] = bf16(acc*scale)
// EPI 2: out[e,k] += sum_d acc*Hu  (atomicAdd)
// ---------------------------------------------------------------------------
template<int EPI, int QMODE>
__global__ __launch_bounds__(256, 2)
void gemm4n(const u16* __restrict__ A, int lda,
            const u16* __restrict__ B, int ldb,
            int MT, int NT, int K,
            u16* __restrict__ o_s, float scale, int ldc,
            const u16* __restrict__ Hu, float* __restrict__ o_e,
            int* __restrict__ qcnt)
{
  __shared__ __align__(16) char lds[49152];
  __shared__ int s_idx;
  char* ldsA = lds;              // 2 x 16KB (each = 2 x 8KB row-halves)
  char* ldsB = lds + 32768;      // 2 x 8KB

  const int tid = threadIdx.x, lane = tid & 63, wave = tid >> 6;
  const int wm = (wave >> 1) * 128;            // wave M base (0 or 128)
  const int wn = (wave & 1) * 64;              // wave N base (0 or 64)
  const int KT = K >> 5;
  const int r15 = lane & 15, g16b = (lane >> 4) * 16;   // byte K-offset

  int xcc;
  asm volatile("s_getreg_b32 %0, hwreg(20, 0, 32)" : "=s"(xcc));  // HW_REG_XCC_ID
  xcc &= 7;
  const int MPX = MT >> 3;
  const int NQ = NT >> 3, NR = NT & 7;

#define STAGE_A32(tk, buf) do { const u16* _g = Ag + (size_t)(tk) * 32; \
    stage_t32(_g,                      lda, (buf),        tid); \
    stage_t32(_g + (size_t)128 * lda,  lda, (buf) + 8192, tid); } while (0)

  for (int dx = 0; dx < 8; ++dx) {
    const int qi = (xcc + dx) & 7;
    int per, ntb = 0, ntc = 0;
    if constexpr (QMODE == 0) {
      per = (MT * NT) >> 3;
    } else {
      ntc = NQ + (qi < NR ? 1 : 0);
      ntb = qi * NQ + (qi < NR ? qi : NR);
      per = ntc * MT;
    }
    while (true) {
      if (tid == 0) s_idx = atomicAdd(&qcnt[qi], 1);
      __syncthreads();
      const int idx = s_idx;
      __syncthreads();
      if (idx >= per) break;
      int mt, nt;
      if constexpr (QMODE == 0) {
        mt = qi * MPX + (idx % MPX); nt = idx / MPX;
      } else {
        const int srw = ntc << 3;            // tiles per super-row
        const int sr = idx / srw, rem = idx - sr * srw;
        nt = ntb + (rem >> 3);               // 8 consecutive pops share nt
        mt = (sr << 3) + (rem & 7);          // A super-slice L2-resident
      }
      const int m0 = mt * 256, n0 = nt * 128;
      const u16* Ag = A + (size_t)m0 * lda;
      const u16* Bg = B + (size_t)n0 * ldb;

      f32x4 acc[8][4];
#pragma unroll
      for (int m = 0; m < 8; ++m)
#pragma unroll
        for (int n = 0; n < 4; ++n) acc[m][n] = f32x4{0.f, 0.f, 0.f, 0.f};

      // prologue: stage t0 + t1 (12 gloads); vmcnt(6) => t0 landed
      STAGE_A32(0, ldsA);
      stage_t32(Bg, ldb, ldsB, tid);
      STAGE_A32(1, ldsA + 16384);
      stage_t32(Bg + 32, ldb, ldsB + 8192, tid);
      asm volatile("s_waitcnt vmcnt(6)" ::: "memory");
      barx();

      for (int t = 0; t < KT; ++t) {
        const int par = t & 1;
        const char* Ab = ldsA + par * 16384;
        const char* Bb = ldsB + par * 8192;
        bf16x8 a[8], b[4];
#pragma unroll
        for (int m = 0; m < 8; ++m) {
          const int lr = wm + m * 16 + r15;          // 0..255
          int p = (lr & 127) * 64 + g16b;
          p ^= ((p >> 7) & 3) << 4;
          a[m] = *(const bf16x8*)(Ab + (lr >> 7) * 8192 + p);
        }
#pragma unroll
        for (int n = 0; n < 4; ++n) {
          const int lr = wn + n * 16 + r15;          // 0..127
          int p = lr * 64 + g16b;
          p ^= ((p >> 7) & 3) << 4;
          b[n] = *(const bf16x8*)(Bb + p);
        }
        asm volatile("s_waitcnt lgkmcnt(0)" ::: "memory");
        __builtin_amdgcn_sched_barrier(0);
        barx();                          // all waves' reads of parity-t done
        if (t + 2 < KT) {                // stage t+2 into parity-t (WAR-safe)
          STAGE_A32(t + 2, ldsA + par * 16384);
          stage_t32(Bg + (size_t)(t + 2) * 32, ldb, ldsB + par * 8192, tid);
        }
        __builtin_amdgcn_s_setprio(1);
#pragma unroll
        for (int m = 0; m < 8; ++m)
#pragma unroll
          for (int n = 0; n < 4; ++n)
            acc[m][n] = __builtin_amdgcn_mfma_f32_16x16x32_bf16(
                a[m], b[n], acc[m][n], 0, 0, 0);
        __builtin_amdgcn_s_setprio(0);
        if (t + 2 < KT) asm volatile("s_waitcnt vmcnt(6)" ::: "memory");
        else            asm volatile("s_waitcnt vmcnt(0)" ::: "memory");
        barx();                          // tile t+1 fully in LDS for all waves
      }

      // ---- epilogue ----
      const int rgrp = lane >> 4, cid = lane & 15;
      if constexpr (EPI == 1) {
#pragma unroll
        for (int m = 0; m < 8; ++m)
#pragma unroll
          for (int n = 0; n < 4; ++n)
#pragma unroll
            for (int j = 0; j < 4; ++j) {
              int row = m0 + wm + m * 16 + rgrp * 4 + j;
              int col = n0 + wn + n * 16 + cid;
              o_s[(size_t)row * ldc + col] = f2bf(acc[m][n][j] * scale);
            }
      } else {
        const int kidx  = n0 >> 10;          // 128-wide tile stays in one k
        const int dbase = (n0 & 1023) + wn;
#pragma unroll
        for (int m = 0; m < 8; ++m)
#pragma unroll
          for (int j = 0; j < 4; ++j) {
            int row = m0 + wm + m * 16 + rgrp * 4 + j;
            float p = 0.f;
#pragma unroll
            for (int n = 0; n < 4; ++n)
              p += acc[m][n][j] * bf2f(Hu[(size_t)row * AA + dbase + n * 16 + cid]);
            p += __shfl_xor(p, 1, 64);
            p += __shfl_xor(p, 2, 64);
            p += __shfl_xor(p, 4, 64);
            p += __shfl_xor(p, 8, 64);
            if (cid == 0) atomicAdd(&o_e[(size_t)row * KE + kidx], p);
          }
      }
    }
  }
#undef STAGE_A32
}

// ---------------------------------------------------------------------------
// gemm8: persistent 256x256-tile bf16 GEMM (8 waves, 1 block/CU), continuous
// m201-style 8-phase pipeline + per-XCD queues (super-row mapping).
// Used for the scores GEMM.
// ---------------------------------------------------------------------------
template<int EPI, int QMODE>
__global__ __launch_bounds__(512, 2)
void gemm8(const u16* __restrict__ A, int lda,
           const u16* __restrict__ B, int ldb,
           int MT, int NT, int K,
           u16* __restrict__ o_s, float scale, int ldc,
           const u16* __restrict__ Hu, float* __restrict__ o_e,
           int* __restrict__ qcnt)
{
  __shared__ __align__(16) char lds[131072];
  __shared__ int s_next[3];    // {m0, n0, have}
  char* ldsA = lds;            // [parity 32KB][half 16KB]
  char* ldsB = lds + 65536;

  const int tid = threadIdx.x, lane = tid & 63, wave = tid >> 6;
  const int wm = (wave >> 2) * 128;
  const int wn = (wave & 3) * 64;
  const int wnl = (wave & 1) * 64;
  const int KT = K >> 6, KT2 = KT >> 1;
  const int r15 = lane & 15, g16 = (lane >> 4) << 4;

  int xcc;
  asm volatile("s_getreg_b32 %0, hwreg(20, 0, 32)" : "=s"(xcc));  // HW_REG_XCC_ID
  xcc &= 7;
  const int MPX = MT >> 3;
  const int NQ = NT >> 3, NR = NT & 7;

  const char* Ab_e = ldsA +         (wm >> 7) * 16384;
  const char* Ab_o = ldsA + 32768 + (wm >> 7) * 16384;
  const char* Bb_e = ldsB +         (wn >> 7) * 16384;
  const char* Bb_o = ldsB + 32768 + (wn >> 7) * 16384;

  int dxr = 0;
  auto pop_next = [&]() {
    while (dxr < 8) {
      const int qi = (xcc + dxr) & 7;
      int per, ntb = 0, ntc = 0;
      if constexpr (QMODE == 0) {
        per = (MT * NT) >> 3;
      } else {
        ntc = NQ + (qi < NR ? 1 : 0);
        ntb = qi * NQ + (qi < NR ? qi : NR);
        per = ntc * MT;
      }
      const int idx = atomicAdd(&qcnt[qi], 1);
      if (idx < per) {
        int mt, nt;
        if constexpr (QMODE == 0) {
          mt = qi * MPX + (idx % MPX); nt = idx / MPX;
        } else {
          const int srw = ntc << 3;
          const int sr = idx / srw, rem = idx - sr * srw;
          nt = ntb + (rem >> 3); mt = (sr << 3) + (rem & 7);
        }
        s_next[0] = mt * 256; s_next[1] = nt * 256; s_next[2] = 1;
        return;
      }
      ++dxr;
    }
    s_next[2] = 0;
  };

  if (tid == 0) pop_next();
  __syncthreads();
  int m0 = s_next[0], n0 = s_next[1];
  if (!s_next[2]) return;

#define STAGE_A2(tk, h) do { const int _tk = (tk); \
    if (_tk < KT) stage_half(A + (size_t)(m0 + (h)*128) * lda + (size_t)_tk*64, lda, \
                             ldsA + (_tk & 1) * 32768 + (h) * 16384, tid); \
    else if (have_n) stage_half(A + (size_t)(m0n + (h)*128) * lda + (size_t)(_tk-KT)*64, lda, \
                                ldsA + (_tk & 1) * 32768 + (h) * 16384, tid); } while (0)
#define STAGE_B2(tk, h) do { const int _tk = (tk); \
    if (_tk < KT) stage_half(B + (size_t)(n0 + (h)*128) * ldb + (size_t)_tk*64, ldb, \
                             ldsB + (_tk & 1) * 32768 + (h) * 16384, tid); \
    else if (have_n) stage_half(B + (size_t)(n0n + (h)*128) * ldb + (size_t)(_tk-KT)*64, ldb, \
                                ldsB + (_tk & 1) * 32768 + (h) * 16384, tid); } while (0)
#define RD_A4(base, q) \
  _Pragma("unroll") for (int m = (q)*4; m < (q)*4+4; ++m) \
  _Pragma("unroll") for (int kk = 0; kk < 2; ++kk) { \
    int p = (m*16 + r15)*128 + kk*64 + g16; p ^= ((p>>7)&7)<<4; \
    a[m][kk] = *(const bf16x8*)((base) + p); }
#define RD_B2(base, q) \
  _Pragma("unroll") for (int n = (q)*2; n < (q)*2+2; ++n) \
  _Pragma("unroll") for (int kk = 0; kk < 2; ++kk) { \
    int p = (wnl + n*16 + r15)*128 + kk*64 + g16; p ^= ((p>>7)&7)<<4; \
    b[n][kk] = *(const bf16x8*)((base) + p); }
#define MM(QM, QN) do { \
  __builtin_amdgcn_s_setprio(1); \
  _Pragma("unroll") for (int kk = 0; kk < 2; ++kk) \
  _Pragma("unroll") for (int m = 0; m < 4; ++m) \
  _Pragma("unroll") for (int n = 0; n < 2; ++n) \
    acc[(QM)*4+m][(QN)*2+n] = __builtin_amdgcn_mfma_f32_16x16x32_bf16( \
        a[(QM)*4+m][kk], b[(QN)*2+n][kk], acc[(QM)*4+m][(QN)*2+n], 0, 0, 0); \
  __builtin_amdgcn_s_setprio(0); } while (0)
#define WAIT_LGKM0 do { asm volatile("s_waitcnt lgkmcnt(0)" ::: "memory"); \
                        __builtin_amdgcn_sched_barrier(0); } while (0)
#define KTILE(t, AB, BB) do { \
    RD_B2(BB, 0); RD_A4(AB, 0); \
    STAGE_B2((t) + 1, 1); \
    asm volatile("s_waitcnt lgkmcnt(8)" ::: "memory"); \
    barx(); WAIT_LGKM0; \
    MM(0, 0); \
    barx(); \
    RD_B2(BB, 1); \
    barx(); WAIT_LGKM0; \
    MM(0, 1); \
    barx(); \
    RD_A4(AB, 1); \
    STAGE_B2((t) + 2, 0); \
    barx(); WAIT_LGKM0; \
    MM(1, 1); \
    barx(); \
    STAGE_A2((t) + 2, 0); \
    STAGE_A2((t) + 2, 1); \
    barx(); \
    __builtin_amdgcn_sched_barrier(0); \
    MM(1, 0); \
    if (vm6) asm volatile("s_waitcnt vmcnt(6)" ::: "memory"); \
    else     asm volatile("s_waitcnt vmcnt(0)" ::: "memory"); \
    barx(); } while (0)

  {
    const int m0n = 0, n0n = 0; const bool have_n = false; (void)m0n; (void)n0n; (void)have_n;
    STAGE_A2(0, 0); STAGE_A2(0, 1); STAGE_B2(0, 0); STAGE_B2(0, 1);
    STAGE_B2(1, 0); STAGE_A2(1, 0); STAGE_A2(1, 1);
  }
  asm volatile("s_waitcnt vmcnt(6)" ::: "memory");
  barx();

  while (true) {
    f32x4 acc[8][4];
#pragma unroll
    for (int m = 0; m < 8; ++m)
#pragma unroll
      for (int n = 0; n < 4; ++n) acc[m][n] = f32x4{0.f, 0.f, 0.f, 0.f};

    int m0n = 0, n0n = 0;
    bool have_n = false;

    for (int i = 0; i < KT2; ++i) {
      const int ta = 2 * i, tb = 2 * i + 1;
      if (i == KT2 - 2 && tid == 0) pop_next();
      if (i == KT2 - 1) { m0n = s_next[0]; n0n = s_next[1]; have_n = (s_next[2] != 0); }
      const bool tail = (i == KT2 - 1);
      const bool vm6 = !tail || have_n;
      bf16x8 a[8][2], b[4][2];
      KTILE(ta, Ab_e, Bb_e);
      KTILE(tb, Ab_o, Bb_o);
    }

    const int rgrp = lane >> 4, cid = lane & 15;
    if constexpr (EPI == 1) {
#pragma unroll
      for (int m = 0; m < 8; ++m)
#pragma unroll
        for (int n = 0; n < 4; ++n)
#pragma unroll
          for (int j = 0; j < 4; ++j) {
            int row = m0 + wm + m * 16 + rgrp * 4 + j;
            int col = n0 + wn + n * 16 + cid;
            o_s[(size_t)row * ldc + col] = f2bf(acc[m][n][j] * scale);
          }
    } else {
      const int kidx  = n0 >> 10;
      const int dbase = (n0 & 1023) + wn;
#pragma unroll
      for (int m = 0; m < 8; ++m)
#pragma unroll
        for (int j = 0; j < 4; ++j) {
          int row = m0 + wm + m * 16 + rgrp * 4 + j;
          float p = 0.f;
#pragma unroll
          for (int n = 0; n < 4; ++n)
            p += acc[m][n][j] * bf2f(Hu[(size_t)row * AA + dbase + n * 16 + cid]);
          p += __shfl_xor(p, 1, 64);
          p += __shfl_xor(p, 2, 64);
          p += __shfl_xor(p, 4, 64);
          p += __shfl_xor(p, 8, 64);
          if (cid == 0) atomicAdd(&o_e[(size_t)row * KE + kidx], p);
        }
    }

    if (!have_n) break;
    m0 = m0n; n0 = n0n;
  }
#undef STAGE_A2
#undef STAGE_B2
#undef RD_A4
#undef RD_B2
#undef MM
#undef WAIT_LGKM0
#undef KTILE
}

// ---------------------------------------------------------------------------
// Generic 128x128-tile bf16 GEMM, C = A @ B^T (2-phase; QKV / PV / fallbacks)
// ---------------------------------------------------------------------------
#define BM 128
#define BN 128
#define BK 64

template<int EPI, bool BF32>
__global__ __launch_bounds__(256)
void gemm_bt(const u16* __restrict__ A, int lda,
             const void* __restrict__ Bptr, int ldb,
             int MT, int NT, int K,
             u16* __restrict__ o_q, u16* __restrict__ o_k, u16* __restrict__ o_vt,
             const float* __restrict__ biasc,
             u16* __restrict__ o_s, float scale, int ldc,
             const u16* __restrict__ Hu, float* __restrict__ o_e)
{
  const int nb  = MT * NT;
  const int per = nb >> 3;                    // grids are multiples of 8
  int bid = blockIdx.x;
  bid = (bid & 7) * per + (bid >> 3);         // XCD-contiguous chunks
  const int mt = bid % MT, nt = bid / MT;     // mt fast => B panel L2 reuse
  const int m0 = mt * BM, n0 = nt * BN;

  __shared__ u16 As[BM * BK];
  __shared__ u16 Bs[BN * BK];

  const int tid  = threadIdx.x;
  const int lane = tid & 63, wave = tid >> 6;
  const int wm = (wave >> 1) * 64, wn = (wave & 1) * 64;

  f32x4 acc[4][4];
#pragma unroll
  for (int m = 0; m < 4; ++m)
#pragma unroll
    for (int n = 0; n < 4; ++n) acc[m][n] = f32x4{0.f, 0.f, 0.f, 0.f};

  const u16*   Bh = (const u16*)Bptr;
  const float* Bf = (const float*)Bptr;

  const int KT = K / BK;
  for (int kt = 0; kt < KT; ++kt) {
    const int k0 = kt * BK;
#pragma unroll
    for (int it = 0; it < 4; ++it) {
      int o = it * 4096 + wave * 1024 + lane * 16;
      int r = o >> 7;
      int c = (o & 127) >> 1;
      gload16(A + (size_t)(m0 + r) * lda + k0 + c,
              &As[(it * 4096 + wave * 1024) >> 1]);
    }
    if constexpr (!BF32) {
#pragma unroll
      for (int it = 0; it < 4; ++it) {
        int o = it * 4096 + wave * 1024 + lane * 16;
        int r = o >> 7;
        int c = (o & 127) >> 1;
        gload16(Bh + (size_t)(n0 + r) * ldb + k0 + c,
                &Bs[(it * 4096 + wave * 1024) >> 1]);
      }
    } else {
#pragma unroll
      for (int it = 0; it < 8; ++it) {
        int e = it * 1024 + tid * 4;
        int r = e >> 6, c = e & 63;
        const float4 v = *(const float4*)(Bf + (size_t)(n0 + r) * ldb + k0 + c);
        ushort4 h;
        h.x = f2bf(v.x); h.y = f2bf(v.y); h.z = f2bf(v.z); h.w = f2bf(v.w);
        *(ushort4*)&Bs[r * BK + c] = h;
      }
    }
    asm volatile("s_waitcnt vmcnt(0)" ::: "memory");
    __syncthreads();

#pragma unroll
    for (int kk = 0; kk < 2; ++kk) {
      const int ro = lane & 15;
      const int ko = kk * 32 + (lane >> 4) * 8;
      bf16x8 af[4], bfg[4];
#pragma unroll
      for (int m = 0; m < 4; ++m)
        af[m] = *(const bf16x8*)&As[(wm + m * 16 + ro) * BK + ko];
#pragma unroll
      for (int n = 0; n < 4; ++n)
        bfg[n] = *(const bf16x8*)&Bs[(wn + n * 16 + ro) * BK + ko];
#pragma unroll
      for (int m = 0; m < 4; ++m)
#pragma unroll
        for (int n = 0; n < 4; ++n)
          acc[m][n] = __builtin_amdgcn_mfma_f32_16x16x32_bf16(
              af[m], bfg[n], acc[m][n], 0, 0, 0);
    }
    __syncthreads();
  }

  const int rgrp = lane >> 4, cid = lane & 15;

  if constexpr (EPI == 0) {
#pragma unroll
    for (int m = 0; m < 4; ++m)
#pragma unroll
      for (int n = 0; n < 4; ++n)
#pragma unroll
        for (int j = 0; j < 4; ++j) {
          int row = m0 + wm + m * 16 + rgrp * 4 + j;
          int col = n0 + wn + n * 16 + cid;
          float v = acc[m][n][j] + biasc[col];
          u16 h = f2bf(v);
          if (col < 1024)       o_q[(size_t)row * AA + col] = h;
          else if (col < 2048)  o_k[(size_t)row * AA + (col - 1024)] = h;
          else                  o_vt[(size_t)(col - 2048) * NTOK + row] = h;
        }
  } else if constexpr (EPI == 1) {
#pragma unroll
    for (int m = 0; m < 4; ++m)
#pragma unroll
      for (int n = 0; n < 4; ++n)
#pragma unroll
        for (int j = 0; j < 4; ++j) {
          int row = m0 + wm + m * 16 + rgrp * 4 + j;
          int col = n0 + wn + n * 16 + cid;
          o_s[(size_t)row * ldc + col] = f2bf(acc[m][n][j] * scale);
        }
  } else {
    const int kidx  = n0 >> 10;
    const int dbase = (n0 & 1023) + wn;
#pragma unroll
    for (int m = 0; m < 4; ++m)
#pragma unroll
      for (int j = 0; j < 4; ++j) {
        int row = m0 + wm + m * 16 + rgrp * 4 + j;
        float p = 0.f;
#pragma unroll
        for (int n = 0; n < 4; ++n) {
          int d = dbase + n * 16 + cid;
          p += acc[m][n][j] * bf2f(Hu[(size_t)row * AA + d]);
        }
        p += __shfl_xor(p, 1, 64);
        p += __shfl_xor(p, 2, 64);
        p += __shfl_xor(p, 4, 64);
        p += __shfl_xor(p, 8, 64);
        if (cid == 0) atomicAdd(&o_e[(size_t)row * KE + kidx], p);
      }
  }
}

// ---------------------------------------------------------------------------
// Row softmax over 8192 bf16 columns, in place. One block per row.
// ---------------------------------------------------------------------------
__global__ __launch_bounds__(256)
void softmax_rows(u16* __restrict__ S)
{
  const size_t base = (size_t)blockIdx.x * 8192;
  const int tid = threadIdx.x;
  const int lane = tid & 63, wave = tid >> 6;
  float v[32];
#pragma unroll
  for (int c = 0; c < 4; ++c) {
    u16x8 u = *(const u16x8*)&S[base + c * 2048 + tid * 8];
#pragma unroll
    for (int j = 0; j < 8; ++j) v[c * 8 + j] = bf2f(u[j]);
  }
  float mx = -1e30f;
#pragma unroll
  for (int i = 0; i < 32; ++i) mx = fmaxf(mx, v[i]);
#pragma unroll
  for (int off = 1; off < 64; off <<= 1) mx = fmaxf(mx, __shfl_xor(mx, off, 64));
  __shared__ float r1[4], r2[4];
  if (lane == 0) r1[wave] = mx;
  __syncthreads();
  mx = fmaxf(fmaxf(r1[0], r1[1]), fmaxf(r1[2], r1[3]));

  float s = 0.f;
#pragma unroll
  for (int i = 0; i < 32; ++i) { v[i] = __expf(v[i] - mx); s += v[i]; }
#pragma unroll
  for (int off = 1; off < 64; off <<= 1) s += __shfl_xor(s, off, 64);
  if (lane == 0) r2[wave] = s;
  __syncthreads();
  s = r2[0] + r2[1] + r2[2] + r2[3];
  const float inv = 1.f / s;
#pragma unroll
  for (int c = 0; c < 4; ++c) {
    u16x8 u;
#pragma unroll
    for (int j = 0; j < 8; ++j) u[j] = f2bf(v[c * 8 + j] * inv);
    *(u16x8*)&S[base + c * 2048 + tid * 8] = u;
  }
}

// ---------------------------------------------------------------------------
// Gather Hu/Hv rows from attn_emb. Handles data delivered as int64 OR int32.
// ---------------------------------------------------------------------------
__global__ __launch_bounds__(256)
void gather_rows(const unsigned* __restrict__ dw, const u16* __restrict__ AE,
                 u16* __restrict__ Hu, u16* __restrict__ Hv)
{
  bool i64 = true;
#pragma unroll
  for (int w = 1; w < 32; w += 2) i64 = i64 && (dw[w] == 0u);
  const int e = blockIdx.x;
  const unsigned iu = i64 ? dw[4 * e]     : dw[2 * e];
  const unsigned iv = i64 ? dw[4 * e + 2] : dw[2 * e + 1];
  const int t = threadIdx.x;
  *(ushort4*)&Hu[(size_t)e * AA + t * 4] = *(const ushort4*)&AE[(size_t)iu * AA + t * 4];
  *(ushort4*)&Hv[(size_t)e * AA + t * 4] = *(const ushort4*)&AE[(size_t)iv * AA + t * 4];
}

// zero d_out + build concatenated bias + zero per-XCD work queues
__global__ __launch_bounds__(256)
void init_misc(float* __restrict__ out_e, const float* __restrict__ bq,
               const float* __restrict__ bk, const float* __restrict__ bv,
               float* __restrict__ biasc, int* __restrict__ qall)
{
  const int i = blockIdx.x * 256 + threadIdx.x;
  if (i < EE * KE) out_e[i] = 0.f;
  if (i < 1024) {
    biasc[i]        = bq[i];
    biasc[1024 + i] = bk[i];
    biasc[2048 + i] = bv[i];
  }
  if (i < 64) qall[i] = 0;
}

// grid-stride f32 -> bf16 conversion, float4 granularity
__global__ __launch_bounds__(256)
void cvt_f32_bf16_v4(const float* __restrict__ src, u16* __restrict__ dst, int n4)
{
  for (int i = blockIdx.x * 256 + threadIdx.x; i < n4; i += gridDim.x * 256) {
    float4 v = ((const float4*)src)[i];
    ushort4 h; h.x = f2bf(v.x); h.y = f2bf(v.y); h.z = f2bf(v.z); h.w = f2bf(v.w);
    ((ushort4*)dst)[i] = h;
  }
}

// WqkvT[n][d] = W*(d, n&1023) for n in [0,3072)
__global__ __launch_bounds__(256)
void build_wT(const float* __restrict__ Wq, const float* __restrict__ Wk,
              const float* __restrict__ Wv, u16* __restrict__ WT)
{
  const int nn = blockIdx.x;    // 0..3071
  const int d  = threadIdx.x;   // 0..255
  const float* W = (nn < 1024) ? Wq : ((nn < 2048) ? Wk : Wv);
  WT[nn * DIM + d] = f2bf(W[(size_t)d * AA + (nn & 1023)]);
}

// ---------------------------------------------------------------------------
extern "C" void kernel_launch(void* const* d_in, const int* in_sizes, int n_in,
                              void* d_out, int out_size, void* d_ws, size_t ws_size,
                              hipStream_t stream)
{
  (void)in_sizes; (void)out_size;
  if (n_in < 9) return;
  const float*    emb  = (const float*)d_in[0];
  const unsigned* data = (const unsigned*)d_in[1];
  const float* Wq = (const float*)d_in[2];
  const float* bq = (const float*)d_in[3];
  const float* Wk = (const float*)d_in[4];
  const float* bk = (const float*)d_in[5];
  const float* Wv = (const float*)d_in[6];
  const float* bv = (const float*)d_in[7];
  const float* We = (const float*)d_in[8];
  float* out = (float*)d_out;

  char* ws = (char*)d_ws;
  size_t off = 0;
  auto alloc = [&](size_t bytes) -> void* {
    void* p = ws + off;
    off += (bytes + 255) & ~(size_t)255;
    return p;
  };
  u16*   emb_b = (u16*)alloc((size_t)NTOK * DIM * 2);     //  4.2 MB
  u16*   WT    = (u16*)alloc((size_t)3072 * DIM * 2);     //  1.6 MB
  float* biasc = (float*)alloc(3072 * 4);
  int*   qall  = (int*)alloc(64 * 4);                     // 8 x 8 XCD queues
  u16*   Qb    = (u16*)alloc((size_t)NTOK * AA * 2);      // 16.8 MB
  u16*   Kb    = (u16*)alloc((size_t)NTOK * AA * 2);
  u16*   Vt    = (u16*)alloc((size_t)AA * NTOK * 2);
  u16*   AE    = (u16*)alloc((size_t)NTOK * AA * 2);
  u16*   Hu    = (u16*)alloc((size_t)EE * AA * 2);        //  8.4 MB
  u16*   Hv    = (u16*)alloc((size_t)EE * AA * 2);

  // bf16 copy of W_edge (136 MB) if it fits alongside a score chunk
  const size_t webf_bytes = ((size_t)KE * AA * AA * 2 + 255) & ~(size_t)255;
  u16* We_b = nullptr;
  if (off + webf_bytes + (size_t)1024 * NTOK * 2 <= ws_size) {
    We_b = (u16*)(ws + off);
    off += webf_bytes;
  }

  int chunk = 4096;  // Sc = 64 MB stays L3-resident for softmax + PV
  while (chunk > 128 && off + (size_t)chunk * NTOK * 2 > ws_size) chunk >>= 1;
  u16* Sc = (u16*)alloc((size_t)chunk * NTOK * 2);
  if (off > ws_size) {
    fprintf(stderr, "kernel_launch: ws too small (need %zu, have %zu)\n", off, ws_size);
    return;
  }

  init_misc<<<(EE * KE) / 256, 256, 0, stream>>>(out, bq, bk, bv, biasc, qall);
  cvt_f32_bf16_v4<<<2048, 256, 0, stream>>>(emb, emb_b, NTOK * DIM / 4);
  build_wT<<<3072, 256, 0, stream>>>(Wq, Wk, Wv, WT);
  if (We_b)
    cvt_f32_bf16_v4<<<4096, 256, 0, stream>>>(We, We_b, KE * AA * AA / 4);

  // QKV: (8192,3072,256) on the 128^2 kernel (K too small for the pipelines)
  gemm_bt<0, false><<<64 * 24, 256, 0, stream>>>(
      emb_b, DIM, WT, DIM, 64, 24, DIM,
      Qb, Kb, Vt, biasc, nullptr, 0.f, 0, nullptr, nullptr);

  // attention, Q-chunked
  const int nch = NTOK / chunk;
  for (int ci = 0; ci < nch; ++ci) {
    const u16* Qc = Qb + (size_t)ci * chunk * AA;
    const bool big = ((chunk & 2047) == 0);   // MT multiple of 8
    if (big)
      gemm8<1, 1><<<256, 512, 0, stream>>>(
          Qc, AA, Kb, AA, chunk / 256, 32, AA,
          Sc, 0.0625f, NTOK, nullptr, nullptr, qall + 8 * ci);
    else
      gemm_bt<1, false><<<(chunk / 128) * 64, 256, 0, stream>>>(
          Qc, AA, Kb, AA, chunk / 128, 64, AA,
          nullptr, nullptr, nullptr, nullptr, Sc, 0.0625f, NTOK, nullptr, nullptr);
    softmax_rows<<<chunk, 256, 0, stream>>>(Sc);
    // PV on the 128^2 kernel: (chunk/128)*8 = 256 blocks = full machine
    gemm_bt<1, false><<<(chunk / 128) * 8, 256, 0, stream>>>(
        Sc, NTOK, Vt, NTOK, chunk / 128, 8, NTOK,
        nullptr, nullptr, nullptr, nullptr,
        AE + (size_t)ci * chunk * AA, 1.0f, AA, nullptr, nullptr);
  }

  gather_rows<<<EE, 256, 0, stream>>>(data, AE, Hu, Hv);

  // edge bilinear on gemm4n: 256x128 tile, 384B-LDS/MFMA, 2 blocks/CU
  if (We_b)
    gemm4n<2, 1><<<512, 256, 0, stream>>>(
        Hv, AA, We_b, AA, 16, 520, AA,
        nullptr, 0.f, 0, Hu, out, qall + 32);
  else
    gemm_bt<3, true><<<32 * 520, 256, 0, stream>>>(
        Hv, AA, We, AA, 32, 520, AA,
        nullptr, nullptr, nullptr, nullptr, nullptr, 0.f, 0, Hu, out);
}

// Round 16
// 1488.104 us; speedup vs baseline: 1.0613x; 1.0055x over previous
//
#include <hip/hip_runtime.h>
#include <cstdio>
#include <cstdint>

// Problem constants: N=8192 tokens, D=256, A=1024, K=65 edge types, E=4096 edges.
#define NTOK 8192
#define DIM  256
#define AA   1024
#define KE   65
#define EE   4096

typedef unsigned short u16;
typedef __attribute__((ext_vector_type(4))) float   f32x4;
typedef __attribute__((ext_vector_type(8))) short   bf16x8;
typedef __attribute__((ext_vector_type(8))) unsigned short u16x8;

#define DEVI __device__ __forceinline__

DEVI u16 f2bf(float f) {               // RNE f32 -> bf16 bits
  union { float f; unsigned u; } x; x.f = f;
  unsigned r = x.u + 0x7FFFu + ((x.u >> 16) & 1u);
  return (u16)(r >> 16);
}
DEVI float bf2f(u16 h) {
  union { unsigned u; float f; } x; x.u = ((unsigned)h) << 16;
  return x.f;
}

DEVI void gload16(const void* g, void* l) {
  __builtin_amdgcn_global_load_lds(
      (const __attribute__((address_space(1))) void*)g,
      (__attribute__((address_space(3))) void*)l,
      16, 0, 0);
}

DEVI void barx() {
  asm volatile("" ::: "memory");
  __builtin_amdgcn_s_barrier();
  asm volatile("" ::: "memory");
}

// Stage one 128x64 bf16 half-tile global->LDS (linear dest, pre-swizzled src).
// Swizzle: physical byte o holds logical byte q = o ^ (((o>>7)&7)<<4).
DEVI void stage_half(const u16* __restrict__ g0, int ld, char* dst, int tid) {
#pragma unroll
  for (int rr = 0; rr < 2; ++rr) {
    int o = rr * 8192 + (tid >> 6) * 1024 + (tid & 63) * 16;
    int q = o ^ (((o >> 7) & 7) << 4);
    gload16(g0 + (size_t)(q >> 7) * ld + ((q & 127) >> 1),
            dst + rr * 8192 + (tid >> 6) * 1024);
  }
}

// ---------------------------------------------------------------------------
// Persistent 256x256-tile bf16 GEMM, C = A @ B^T, per-XCD work queues,
// CONTINUOUS pipeline: m201 stagger (tile t stages [t+1]Bh1 + [t+2]{Bh0,Ah0,
// Ah1}; vmcnt(6) only at phase ends, 3 halves always in flight); the last
// K-tile-pair's 7 stage slots pre-stage the NEXT tile's prologue halves, so
// tiles chain with zero cold-start; epilogue overlaps the in-flight prefetch.
// QMODE 0: XCD owns an M-slice, sweeps nt.  QMODE 1: XCD owns an NT-slice,
// sweeps mt in super-rows of 8.  Work-stealing across queues for completion.
// EPI 1: o_s[row*ldc+col] = bf16(acc*scale)
// EPI 2: out[e,k] += sum_d acc*Hu  (atomicAdd)
// ---------------------------------------------------------------------------
template<int EPI, int QMODE>
__global__ __launch_bounds__(512, 2)
void gemm8(const u16* __restrict__ A, int lda,
           const u16* __restrict__ B, int ldb,
           int MT, int NT, int K,
           u16* __restrict__ o_s, float scale, int ldc,
           const u16* __restrict__ Hu, float* __restrict__ o_e,
           int* __restrict__ qcnt)
{
  __shared__ __align__(16) char lds[131072];
  __shared__ int s_next[3];    // {m0, n0, have}
  char* ldsA = lds;            // [parity 32KB][half 16KB]
  char* ldsB = lds + 65536;

  const int tid = threadIdx.x, lane = tid & 63, wave = tid >> 6;
  const int wm = (wave >> 2) * 128;            // wave's A half = wm>>7
  const int wn = (wave & 3) * 64;              // wave's B half = wn>>7
  const int wnl = (wave & 1) * 64;             // row base within B half
  const int KT = K >> 6, KT2 = KT >> 1;
  const int r15 = lane & 15, g16 = (lane >> 4) << 4;

  int xcc;
  asm volatile("s_getreg_b32 %0, hwreg(20, 0, 32)" : "=s"(xcc));  // HW_REG_XCC_ID
  xcc &= 7;
  const int MPX = MT >> 3;                     // QMODE 0: MT multiple of 8
  const int NQ = NT >> 3, NR = NT & 7;         // QMODE 1: nt-slice sizing

  const char* Ab_e = ldsA +         (wm >> 7) * 16384;
  const char* Ab_o = ldsA + 32768 + (wm >> 7) * 16384;
  const char* Bb_e = ldsB +         (wn >> 7) * 16384;
  const char* Bb_o = ldsB + 32768 + (wn >> 7) * 16384;

  int dxr = 0;                                 // tid0-private steal cursor
  auto pop_next = [&]() {                      // tid==0 only; fills s_next
    while (dxr < 8) {
      const int qi = (xcc + dxr) & 7;
      int per, ntb = 0, ntc = 0;
      if constexpr (QMODE == 0) {
        per = (MT * NT) >> 3;
      } else {
        ntc = NQ + (qi < NR ? 1 : 0);
        ntb = qi * NQ + (qi < NR ? qi : NR);
        per = ntc * MT;
      }
      const int idx = atomicAdd(&qcnt[qi], 1);
      if (idx < per) {
        int mt, nt;
        if constexpr (QMODE == 0) {
          mt = qi * MPX + (idx % MPX); nt = idx / MPX;
        } else {
          const int srw = ntc << 3;
          const int sr = idx / srw, rem = idx - sr * srw;
          nt = ntb + (rem >> 3); mt = (sr << 3) + (rem & 7);
        }
        s_next[0] = mt * 256; s_next[1] = nt * 256; s_next[2] = 1;
        return;
      }
      ++dxr;
    }
    s_next[2] = 0;
  };

  if (tid == 0) pop_next();
  __syncthreads();
  int m0 = s_next[0], n0 = s_next[1];
  if (!s_next[2]) return;

  // stage k-tile tk (tk may be >= KT -> next tile's tk-KT, if have_n)
#define STAGE_A2(tk, h) do { const int _tk = (tk); \
    if (_tk < KT) stage_half(A + (size_t)(m0 + (h)*128) * lda + (size_t)_tk*64, lda, \
                             ldsA + (_tk & 1) * 32768 + (h) * 16384, tid); \
    else if (have_n) stage_half(A + (size_t)(m0n + (h)*128) * lda + (size_t)(_tk-KT)*64, lda, \
                                ldsA + (_tk & 1) * 32768 + (h) * 16384, tid); } while (0)
#define STAGE_B2(tk, h) do { const int _tk = (tk); \
    if (_tk < KT) stage_half(B + (size_t)(n0 + (h)*128) * ldb + (size_t)_tk*64, ldb, \
                             ldsB + (_tk & 1) * 32768 + (h) * 16384, tid); \
    else if (have_n) stage_half(B + (size_t)(n0n + (h)*128) * ldb + (size_t)(_tk-KT)*64, ldb, \
                                ldsB + (_tk & 1) * 32768 + (h) * 16384, tid); } while (0)
#define RD_A4(base, q) \
  _Pragma("unroll") for (int m = (q)*4; m < (q)*4+4; ++m) \
  _Pragma("unroll") for (int kk = 0; kk < 2; ++kk) { \
    int p = (m*16 + r15)*128 + kk*64 + g16; p ^= ((p>>7)&7)<<4; \
    a[m][kk] = *(const bf16x8*)((base) + p); }
#define RD_B2(base, q) \
  _Pragma("unroll") for (int n = (q)*2; n < (q)*2+2; ++n) \
  _Pragma("unroll") for (int kk = 0; kk < 2; ++kk) { \
    int p = (wnl + n*16 + r15)*128 + kk*64 + g16; p ^= ((p>>7)&7)<<4; \
    b[n][kk] = *(const bf16x8*)((base) + p); }
#define MM(QM, QN) do { \
  __builtin_amdgcn_s_setprio(1); \
  _Pragma("unroll") for (int kk = 0; kk < 2; ++kk) \
  _Pragma("unroll") for (int m = 0; m < 4; ++m) \
  _Pragma("unroll") for (int n = 0; n < 2; ++n) \
    acc[(QM)*4+m][(QN)*2+n] = __builtin_amdgcn_mfma_f32_16x16x32_bf16( \
        a[(QM)*4+m][kk], b[(QN)*2+n][kk], acc[(QM)*4+m][(QN)*2+n], 0, 0, 0); \
  __builtin_amdgcn_s_setprio(0); } while (0)
#define WAIT_LGKM0 do { asm volatile("s_waitcnt lgkmcnt(0)" ::: "memory"); \
                        __builtin_amdgcn_sched_barrier(0); } while (0)
// one K-tile: 4 phases (reads quadrant-paired; stagger slots per m201)
#define KTILE(t, AB, BB) do { \
    /* q0: b01+a03 (12 reads); stage B(t+1,h1) */ \
    RD_B2(BB, 0); RD_A4(AB, 0); \
    STAGE_B2((t) + 1, 1); \
    asm volatile("s_waitcnt lgkmcnt(8)" ::: "memory"); \
    barx(); WAIT_LGKM0; \
    MM(0, 0); \
    barx(); \
    /* q1: b23 (4 reads); no stage */ \
    RD_B2(BB, 1); \
    barx(); WAIT_LGKM0; \
    MM(0, 1); \
    barx(); \
    /* q2: a47 (8 reads); stage B(t+2,h0) */ \
    RD_A4(AB, 1); \
    STAGE_B2((t) + 2, 0); \
    barx(); WAIT_LGKM0; \
    MM(1, 1); \
    barx(); \
    /* q3: no reads; stage A(t+2,h0)+A(t+2,h1); counted vmcnt */ \
    STAGE_A2((t) + 2, 0); \
    STAGE_A2((t) + 2, 1); \
    barx(); \
    __builtin_amdgcn_sched_barrier(0); \
    MM(1, 0); \
    if (vm6) asm volatile("s_waitcnt vmcnt(6)" ::: "memory"); \
    else     asm volatile("s_waitcnt vmcnt(0)" ::: "memory"); \
    barx(); } while (0)

  // ---- prologue: tile0 (4 halves) + {B(1,h0), A(1,h0), A(1,h1)} ----
  {
    const int m0n = 0, n0n = 0; const bool have_n = false; (void)m0n; (void)n0n; (void)have_n;
    STAGE_A2(0, 0); STAGE_A2(0, 1); STAGE_B2(0, 0); STAGE_B2(0, 1);
    STAGE_B2(1, 0); STAGE_A2(1, 0); STAGE_A2(1, 1);
  }
  asm volatile("s_waitcnt vmcnt(6)" ::: "memory");
  barx();

  while (true) {
    f32x4 acc[8][4];
#pragma unroll
    for (int m = 0; m < 8; ++m)
#pragma unroll
      for (int n = 0; n < 4; ++n) acc[m][n] = f32x4{0.f, 0.f, 0.f, 0.f};

    int m0n = 0, n0n = 0;
    bool have_n = false;

    for (int i = 0; i < KT2; ++i) {
      const int ta = 2 * i, tb = 2 * i + 1;
      if (i == KT2 - 2 && tid == 0) pop_next();   // visible >=8 barriers later
      if (i == KT2 - 1) { m0n = s_next[0]; n0n = s_next[1]; have_n = (s_next[2] != 0); }
      const bool tail = (i == KT2 - 1);
      const bool vm6 = !tail || have_n;
      bf16x8 a[8][2], b[4][2];
      KTILE(ta, Ab_e, Bb_e);      // even parity
      KTILE(tb, Ab_o, Bb_o);      // odd parity
    }

    // ---- epilogue (registers + global only; runs under in-flight prefetch) --
    const int rgrp = lane >> 4, cid = lane & 15;
    if constexpr (EPI == 1) {
#pragma unroll
      for (int m = 0; m < 8; ++m)
#pragma unroll
        for (int n = 0; n < 4; ++n)
#pragma unroll
          for (int j = 0; j < 4; ++j) {
            int row = m0 + wm + m * 16 + rgrp * 4 + j;
            int col = n0 + wn + n * 16 + cid;
            o_s[(size_t)row * ldc + col] = f2bf(acc[m][n][j] * scale);
          }
    } else {
      const int kidx  = n0 >> 10;             // 256-tile stays within one k
      const int dbase = (n0 & 1023) + wn;
#pragma unroll
      for (int m = 0; m < 8; ++m)
#pragma unroll
        for (int j = 0; j < 4; ++j) {
          int row = m0 + wm + m * 16 + rgrp * 4 + j;
          float p = 0.f;
#pragma unroll
          for (int n = 0; n < 4; ++n)
            p += acc[m][n][j] * bf2f(Hu[(size_t)row * AA + dbase + n * 16 + cid]);
          p += __shfl_xor(p, 1, 64);
          p += __shfl_xor(p, 2, 64);
          p += __shfl_xor(p, 4, 64);
          p += __shfl_xor(p, 8, 64);
          if (cid == 0) atomicAdd(&o_e[(size_t)row * KE + kidx], p);
        }
    }

    if (!have_n) break;
    m0 = m0n; n0 = n0n;          // next tile's prologue is already in flight
  }
#undef STAGE_A2
#undef STAGE_B2
#undef RD_A4
#undef RD_B2
#undef MM
#undef WAIT_LGKM0
#undef KTILE
}

// ---------------------------------------------------------------------------
// Generic 128x128-tile bf16 GEMM, C = A @ B^T (2-phase; QKV / PV / fallbacks)
// ---------------------------------------------------------------------------
#define BM 128
#define BN 128
#define BK 64

template<int EPI, bool BF32>
__global__ __launch_bounds__(256)
void gemm_bt(const u16* __restrict__ A, int lda,
             const void* __restrict__ Bptr, int ldb,
             int MT, int NT, int K,
             u16* __restrict__ o_q, u16* __restrict__ o_k, u16* __restrict__ o_vt,
             const float* __restrict__ biasc,
             u16* __restrict__ o_s, float scale, int ldc,
             const u16* __restrict__ Hu, float* __restrict__ o_e)
{
  const int nb  = MT * NT;
  const int per = nb >> 3;                    // grids are multiples of 8
  int bid = blockIdx.x;
  bid = (bid & 7) * per + (bid >> 3);         // XCD-contiguous chunks
  const int mt = bid % MT, nt = bid / MT;     // mt fast => B panel L2 reuse
  const int m0 = mt * BM, n0 = nt * BN;

  __shared__ u16 As[BM * BK];
  __shared__ u16 Bs[BN * BK];

  const int tid  = threadIdx.x;
  const int lane = tid & 63, wave = tid >> 6;
  const int wm = (wave >> 1) * 64, wn = (wave & 1) * 64;

  f32x4 acc[4][4];
#pragma unroll
  for (int m = 0; m < 4; ++m)
#pragma unroll
    for (int n = 0; n < 4; ++n) acc[m][n] = f32x4{0.f, 0.f, 0.f, 0.f};

  const u16*   Bh = (const u16*)Bptr;
  const float* Bf = (const float*)Bptr;

  const int KT = K / BK;
  for (int kt = 0; kt < KT; ++kt) {
    const int k0 = kt * BK;
#pragma unroll
    for (int it = 0; it < 4; ++it) {
      int o = it * 4096 + wave * 1024 + lane * 16;
      int r = o >> 7;
      int c = (o & 127) >> 1;
      gload16(A + (size_t)(m0 + r) * lda + k0 + c,
              &As[(it * 4096 + wave * 1024) >> 1]);
    }
    if constexpr (!BF32) {
#pragma unroll
      for (int it = 0; it < 4; ++it) {
        int o = it * 4096 + wave * 1024 + lane * 16;
        int r = o >> 7;
        int c = (o & 127) >> 1;
        gload16(Bh + (size_t)(n0 + r) * ldb + k0 + c,
                &Bs[(it * 4096 + wave * 1024) >> 1]);
      }
    } else {
#pragma unroll
      for (int it = 0; it < 8; ++it) {
        int e = it * 1024 + tid * 4;
        int r = e >> 6, c = e & 63;
        const float4 v = *(const float4*)(Bf + (size_t)(n0 + r) * ldb + k0 + c);
        ushort4 h;
        h.x = f2bf(v.x); h.y = f2bf(v.y); h.z = f2bf(v.z); h.w = f2bf(v.w);
        *(ushort4*)&Bs[r * BK + c] = h;
      }
    }
    asm volatile("s_waitcnt vmcnt(0)" ::: "memory");
    __syncthreads();

#pragma unroll
    for (int kk = 0; kk < 2; ++kk) {
      const int ro = lane & 15;
      const int ko = kk * 32 + (lane >> 4) * 8;
      bf16x8 af[4], bfg[4];
#pragma unroll
      for (int m = 0; m < 4; ++m)
        af[m] = *(const bf16x8*)&As[(wm + m * 16 + ro) * BK + ko];
#pragma unroll
      for (int n = 0; n < 4; ++n)
        bfg[n] = *(const bf16x8*)&Bs[(wn + n * 16 + ro) * BK + ko];
#pragma unroll
      for (int m = 0; m < 4; ++m)
#pragma unroll
        for (int n = 0; n < 4; ++n)
          acc[m][n] = __builtin_amdgcn_mfma_f32_16x16x32_bf16(
              af[m], bfg[n], acc[m][n], 0, 0, 0);
    }
    __syncthreads();
  }

  const int rgrp = lane >> 4, cid = lane & 15;

  if constexpr (EPI == 0) {
#pragma unroll
    for (int m = 0; m < 4; ++m)
#pragma unroll
      for (int n = 0; n < 4; ++n)
#pragma unroll
        for (int j = 0; j < 4; ++j) {
          int row = m0 + wm + m * 16 + rgrp * 4 + j;
          int col = n0 + wn + n * 16 + cid;
          float v = acc[m][n][j] + biasc[col];
          u16 h = f2bf(v);
          if (col < 1024)       o_q[(size_t)row * AA + col] = h;
          else if (col < 2048)  o_k[(size_t)row * AA + (col - 1024)] = h;
          else                  o_vt[(size_t)(col - 2048) * NTOK + row] = h;
        }
  } else if constexpr (EPI == 1) {
#pragma unroll
    for (int m = 0; m < 4; ++m)
#pragma unroll
      for (int n = 0; n < 4; ++n)
#pragma unroll
        for (int j = 0; j < 4; ++j) {
          int row = m0 + wm + m * 16 + rgrp * 4 + j;
          int col = n0 + wn + n * 16 + cid;
          o_s[(size_t)row * ldc + col] = f2bf(acc[m][n][j] * scale);
        }
  } else {
    const int kidx  = n0 >> 10;
    const int dbase = (n0 & 1023) + wn;
#pragma unroll
    for (int m = 0; m < 4; ++m)
#pragma unroll
      for (int j = 0; j < 4; ++j) {
        int row = m0 + wm + m * 16 + rgrp * 4 + j;
        float p = 0.f;
#pragma unroll
        for (int n = 0; n < 4; ++n) {
          int d = dbase + n * 16 + cid;
          p += acc[m][n][j] * bf2f(Hu[(size_t)row * AA + d]);
        }
        p += __shfl_xor(p, 1, 64);
        p += __shfl_xor(p, 2, 64);
        p += __shfl_xor(p, 4, 64);
        p += __shfl_xor(p, 8, 64);
        if (cid == 0) atomicAdd(&o_e[(size_t)row * KE + kidx], p);
      }
  }
}

// ---------------------------------------------------------------------------
// Row softmax over 8192 bf16 columns, in place. One block per row.
// ---------------------------------------------------------------------------
__global__ __launch_bounds__(256)
void softmax_rows(u16* __restrict__ S)
{
  const size_t base = (size_t)blockIdx.x * 8192;
  const int tid = threadIdx.x;
  const int lane = tid & 63, wave = tid >> 6;
  float v[32];
#pragma unroll
  for (int c = 0; c < 4; ++c) {
    u16x8 u = *(const u16x8*)&S[base + c * 2048 + tid * 8];
#pragma unroll
    for (int j = 0; j < 8; ++j) v[c * 8 + j] = bf2f(u[j]);
  }
  float mx = -1e30f;
#pragma unroll
  for (int i = 0; i < 32; ++i) mx = fmaxf(mx, v[i]);
#pragma unroll
  for (int off = 1; off < 64; off <<= 1) mx = fmaxf(mx, __shfl_xor(mx, off, 64));
  __shared__ float r1[4], r2[4];
  if (lane == 0) r1[wave] = mx;
  __syncthreads();
  mx = fmaxf(fmaxf(r1[0], r1[1]), fmaxf(r1[2], r1[3]));

  float s = 0.f;
#pragma unroll
  for (int i = 0; i < 32; ++i) { v[i] = __expf(v[i] - mx); s += v[i]; }
#pragma unroll
  for (int off = 1; off < 64; off <<= 1) s += __shfl_xor(s, off, 64);
  if (lane == 0) r2[wave] = s;
  __syncthreads();
  s = r2[0] + r2[1] + r2[2] + r2[3];
  const float inv = 1.f / s;
#pragma unroll
  for (int c = 0; c < 4; ++c) {
    u16x8 u;
#pragma unroll
    for (int j = 0; j < 8; ++j) u[j] = f2bf(v[c * 8 + j] * inv);
    *(u16x8*)&S[base + c * 2048 + tid * 8] = u;
  }
}

// ---------------------------------------------------------------------------
// Gather Hu/Hv rows from attn_emb. Handles data delivered as int64 OR int32.
// ---------------------------------------------------------------------------
__global__ __launch_bounds__(256)
void gather_rows(const unsigned* __restrict__ dw, const u16* __restrict__ AE,
                 u16* __restrict__ Hu, u16* __restrict__ Hv)
{
  bool i64 = true;
#pragma unroll
  for (int w = 1; w < 32; w += 2) i64 = i64 && (dw[w] == 0u);
  const int e = blockIdx.x;
  const unsigned iu = i64 ? dw[4 * e]     : dw[2 * e];
  const unsigned iv = i64 ? dw[4 * e + 2] : dw[2 * e + 1];
  const int t = threadIdx.x;
  *(ushort4*)&Hu[(size_t)e * AA + t * 4] = *(const ushort4*)&AE[(size_t)iu * AA + t * 4];
  *(ushort4*)&Hv[(size_t)e * AA + t * 4] = *(const ushort4*)&AE[(size_t)iv * AA + t * 4];
}

// zero d_out + build concatenated bias + zero per-XCD work queues
__global__ __launch_bounds__(256)
void init_misc(float* __restrict__ out_e, const float* __restrict__ bq,
               const float* __restrict__ bk, const float* __restrict__ bv,
               float* __restrict__ biasc, int* __restrict__ qall)
{
  const int i = blockIdx.x * 256 + threadIdx.x;
  if (i < EE * KE) out_e[i] = 0.f;
  if (i < 1024) {
    biasc[i]        = bq[i];
    biasc[1024 + i] = bk[i];
    biasc[2048 + i] = bv[i];
  }
  if (i < 64) qall[i] = 0;
}

// grid-stride f32 -> bf16 conversion, float4 granularity
__global__ __launch_bounds__(256)
void cvt_f32_bf16_v4(const float* __restrict__ src, u16* __restrict__ dst, int n4)
{
  for (int i = blockIdx.x * 256 + threadIdx.x; i < n4; i += gridDim.x * 256) {
    float4 v = ((const float4*)src)[i];
    ushort4 h; h.x = f2bf(v.x); h.y = f2bf(v.y); h.z = f2bf(v.z); h.w = f2bf(v.w);
    ((ushort4*)dst)[i] = h;
  }
}

// WqkvT[n][d] = W*(d, n&1023) for n in [0,3072)
__global__ __launch_bounds__(256)
void build_wT(const float* __restrict__ Wq, const float* __restrict__ Wk,
              const float* __restrict__ Wv, u16* __restrict__ WT)
{
  const int nn = blockIdx.x;    // 0..3071
  const int d  = threadIdx.x;   // 0..255
  const float* W = (nn < 1024) ? Wq : ((nn < 2048) ? Wk : Wv);
  WT[nn * DIM + d] = f2bf(W[(size_t)d * AA + (nn & 1023)]);
}

// ---------------------------------------------------------------------------
extern "C" void kernel_launch(void* const* d_in, const int* in_sizes, int n_in,
                              void* d_out, int out_size, void* d_ws, size_t ws_size,
                              hipStream_t stream)
{
  (void)in_sizes; (void)out_size;
  if (n_in < 9) return;
  const float*    emb  = (const float*)d_in[0];
  const unsigned* data = (const unsigned*)d_in[1];
  const float* Wq = (const float*)d_in[2];
  const float* bq = (const float*)d_in[3];
  const float* Wk = (const float*)d_in[4];
  const float* bk = (const float*)d_in[5];
  const float* Wv = (const float*)d_in[6];
  const float* bv = (const float*)d_in[7];
  const float* We = (const float*)d_in[8];
  float* out = (float*)d_out;

  char* ws = (char*)d_ws;
  size_t off = 0;
  auto alloc = [&](size_t bytes) -> void* {
    void* p = ws + off;
    off += (bytes + 255) & ~(size_t)255;
    return p;
  };
  u16*   emb_b = (u16*)alloc((size_t)NTOK * DIM * 2);     //  4.2 MB
  u16*   WT    = (u16*)alloc((size_t)3072 * DIM * 2);     //  1.6 MB
  float* biasc = (float*)alloc(3072 * 4);
  int*   qall  = (int*)alloc(64 * 4);                     // 8 x 8 XCD queues
  u16*   Qb    = (u16*)alloc((size_t)NTOK * AA * 2);      // 16.8 MB
  u16*   Kb    = (u16*)alloc((size_t)NTOK * AA * 2);
  u16*   Vt    = (u16*)alloc((size_t)AA * NTOK * 2);
  u16*   AE    = (u16*)alloc((size_t)NTOK * AA * 2);
  u16*   Hu    = (u16*)alloc((size_t)EE * AA * 2);        //  8.4 MB
  u16*   Hv    = (u16*)alloc((size_t)EE * AA * 2);

  // bf16 copy of W_edge (136 MB) if it fits alongside a score chunk
  const size_t webf_bytes = ((size_t)KE * AA * AA * 2 + 255) & ~(size_t)255;
  u16* We_b = nullptr;
  if (off + webf_bytes + (size_t)1024 * NTOK * 2 <= ws_size) {
    We_b = (u16*)(ws + off);
    off += webf_bytes;
  }

  int chunk = 4096;  // Sc = 64 MB stays L3-resident for softmax + PV
  while (chunk > 128 && off + (size_t)chunk * NTOK * 2 > ws_size) chunk >>= 1;
  u16* Sc = (u16*)alloc((size_t)chunk * NTOK * 2);
  if (off > ws_size) {
    fprintf(stderr, "kernel_launch: ws too small (need %zu, have %zu)\n", off, ws_size);
    return;
  }

  init_misc<<<(EE * KE) / 256, 256, 0, stream>>>(out, bq, bk, bv, biasc, qall);
  cvt_f32_bf16_v4<<<2048, 256, 0, stream>>>(emb, emb_b, NTOK * DIM / 4);
  build_wT<<<3072, 256, 0, stream>>>(Wq, Wk, Wv, WT);
  if (We_b)
    cvt_f32_bf16_v4<<<4096, 256, 0, stream>>>(We, We_b, KE * AA * AA / 4);

  // QKV: (8192,3072,256) on the 128^2 kernel (K too small for the pipeline)
  gemm_bt<0, false><<<64 * 24, 256, 0, stream>>>(
      emb_b, DIM, WT, DIM, 64, 24, DIM,
      Qb, Kb, Vt, biasc, nullptr, 0.f, 0, nullptr, nullptr);

  // attention, Q-chunked
  const int nch = NTOK / chunk;
  for (int ci = 0; ci < nch; ++ci) {
    const u16* Qc = Qb + (size_t)ci * chunk * AA;
    const bool big = ((chunk & 2047) == 0);   // MT multiple of 8
    if (big)
      gemm8<1, 1><<<256, 512, 0, stream>>>(
          Qc, AA, Kb, AA, chunk / 256, 32, AA,
          Sc, 0.0625f, NTOK, nullptr, nullptr, qall + 8 * ci);
    else
      gemm_bt<1, false><<<(chunk / 128) * 64, 256, 0, stream>>>(
          Qc, AA, Kb, AA, chunk / 128, 64, AA,
          nullptr, nullptr, nullptr, nullptr, Sc, 0.0625f, NTOK, nullptr, nullptr);
    softmax_rows<<<chunk, 256, 0, stream>>>(Sc);
    // PV on the 128^2 kernel: (chunk/128)*8 = 256 blocks = full machine
    gemm_bt<1, false><<<(chunk / 128) * 8, 256, 0, stream>>>(
        Sc, NTOK, Vt, NTOK, chunk / 128, 8, NTOK,
        nullptr, nullptr, nullptr, nullptr,
        AE + (size_t)ci * chunk * AA, 1.0f, AA, nullptr, nullptr);
  }

  gather_rows<<<EE, 256, 0, stream>>>(data, AE, Hu, Hv);

  // edge bilinear: T = Hv @ W_all^T fused with Hu-dot epilogue (persistent)
  if (We_b)
    gemm8<2, 1><<<256, 512, 0, stream>>>(
        Hv, AA, We_b, AA, 16, 260, AA,
        nullptr, 0.f, 0, Hu, out, qall + 32);
  else
    gemm_bt<3, true><<<32 * 520, 256, 0, stream>>>(
        Hv, AA, We, AA, 32, 520, AA,
        nullptr, nullptr, nullptr, nullptr, nullptr, 0.f, 0, Hu, out);
}

// Round 17
// 1420.679 us; speedup vs baseline: 1.1117x; 1.0475x over previous
//
#include <hip/hip_runtime.h>
#include <cstdio>
#include <cstdint>

// Problem constants: N=8192 tokens, D=256, A=1024, K=65 edge types, E=4096 edges.
#define NTOK 8192
#define DIM  256
#define AA   1024
#define KE   65
#define EE   4096

typedef unsigned short u16;
typedef __attribute__((ext_vector_type(4))) float   f32x4;
typedef __attribute__((ext_vector_type(8))) short   bf16x8;
typedef __attribute__((ext_vector_type(8))) unsigned short u16x8;

#define DEVI __device__ __forceinline__

DEVI u16 f2bf(float f) {               // RNE f32 -> bf16 bits
  union { float f; unsigned u; } x; x.f = f;
  unsigned r = x.u + 0x7FFFu + ((x.u >> 16) & 1u);
  return (u16)(r >> 16);
}
DEVI float bf2f(u16 h) {
  union { unsigned u; float f; } x; x.u = ((unsigned)h) << 16;
  return x.f;
}

DEVI void gload16(const void* g, void* l) {
  __builtin_amdgcn_global_load_lds(
      (const __attribute__((address_space(1))) void*)g,
      (__attribute__((address_space(3))) void*)l,
      16, 0, 0);
}

DEVI void barx() {
  asm volatile("" ::: "memory");
  __builtin_amdgcn_s_barrier();
  asm volatile("" ::: "memory");
}

// Stage one 128x64 bf16 half-tile global->LDS (linear dest, pre-swizzled src).
// Swizzle: physical byte o holds logical byte q = o ^ (((o>>7)&7)<<4).
DEVI void stage_half(const u16* __restrict__ g0, int ld, char* dst, int tid) {
#pragma unroll
  for (int rr = 0; rr < 2; ++rr) {
    int o = rr * 8192 + (tid >> 6) * 1024 + (tid & 63) * 16;
    int q = o ^ (((o >> 7) & 7) << 4);
    gload16(g0 + (size_t)(q >> 7) * ld + ((q & 127) >> 1),
            dst + rr * 8192 + (tid >> 6) * 1024);
  }
}

// ---------------------------------------------------------------------------
// gemm8s: NON-PERSISTENT 256x256-tile bf16 GEMM, C = A @ B^T, one tile per
// block (grid = MT*NT), XCD-chunked bid swizzle with mt-fastest ordering.
// m201 8-phase schedule per K-tile (stagger: tile t stages [t+1]Bh1 +
// [t+2]{Bh0,Ah0,Ah1}; vmcnt(6) only at phase end, 3 halves in flight).
// This removes the persistent-queue machinery (atomic pops, cross-tile
// chaining, runtime have_n branches inside every stage slot) -- the last
// structural delta vs the verified template.
// EPI 1: o_s[row*ldc+col] = bf16(acc*scale)
// EPI 2: out[e,k] += sum_d acc*Hu  (atomicAdd)
// ---------------------------------------------------------------------------
template<int EPI>
__global__ __launch_bounds__(512, 2)
void gemm8s(const u16* __restrict__ A, int lda,
            const u16* __restrict__ B, int ldb,
            int MT, int NT, int K,
            u16* __restrict__ o_s, float scale, int ldc,
            const u16* __restrict__ Hu, float* __restrict__ o_e)
{
  __shared__ __align__(16) char lds[131072];
  char* ldsA = lds;            // [parity 32KB][half 16KB]
  char* ldsB = lds + 65536;

  const int nb = MT * NT, per = nb >> 3;       // grids are multiples of 8
  int bid = blockIdx.x;
  bid = (bid & 7) * per + (bid >> 3);          // XCD-contiguous chunks
  const int mt = bid % MT, nt = bid / MT;      // mt fastest: B panel reuse
  const int m0 = mt * 256, n0 = nt * 256;

  const int tid = threadIdx.x, lane = tid & 63, wave = tid >> 6;
  const int wm = (wave >> 2) * 128;            // wave's A half = wm>>7
  const int wn = (wave & 3) * 64;              // wave's B half = wn>>7
  const int wnl = (wave & 1) * 64;             // row base within B half
  const int KT = K >> 6;
  const int r15 = lane & 15, g16 = (lane >> 4) << 4;

  const char* Ab_e = ldsA +         (wm >> 7) * 16384;
  const char* Ab_o = ldsA + 32768 + (wm >> 7) * 16384;
  const char* Bb_e = ldsB +         (wn >> 7) * 16384;
  const char* Bb_o = ldsB + 32768 + (wn >> 7) * 16384;

#define STAGE_A2(tk, h) do { const int _tk = (tk); \
    if (_tk < KT) stage_half(A + (size_t)(m0 + (h)*128) * lda + (size_t)_tk*64, lda, \
                             ldsA + (_tk & 1) * 32768 + (h) * 16384, tid); } while (0)
#define STAGE_B2(tk, h) do { const int _tk = (tk); \
    if (_tk < KT) stage_half(B + (size_t)(n0 + (h)*128) * ldb + (size_t)_tk*64, ldb, \
                             ldsB + (_tk & 1) * 32768 + (h) * 16384, tid); } while (0)
#define RD_A4(base, q) \
  _Pragma("unroll") for (int m = (q)*4; m < (q)*4+4; ++m) \
  _Pragma("unroll") for (int kk = 0; kk < 2; ++kk) { \
    int p = (m*16 + r15)*128 + kk*64 + g16; p ^= ((p>>7)&7)<<4; \
    a[m][kk] = *(const bf16x8*)((base) + p); }
#define RD_B2(base, q) \
  _Pragma("unroll") for (int n = (q)*2; n < (q)*2+2; ++n) \
  _Pragma("unroll") for (int kk = 0; kk < 2; ++kk) { \
    int p = (wnl + n*16 + r15)*128 + kk*64 + g16; p ^= ((p>>7)&7)<<4; \
    b[n][kk] = *(const bf16x8*)((base) + p); }
#define MM(QM, QN) do { \
  __builtin_amdgcn_s_setprio(1); \
  _Pragma("unroll") for (int kk = 0; kk < 2; ++kk) \
  _Pragma("unroll") for (int m = 0; m < 4; ++m) \
  _Pragma("unroll") for (int n = 0; n < 2; ++n) \
    acc[(QM)*4+m][(QN)*2+n] = __builtin_amdgcn_mfma_f32_16x16x32_bf16( \
        a[(QM)*4+m][kk], b[(QN)*2+n][kk], acc[(QM)*4+m][(QN)*2+n], 0, 0, 0); \
  __builtin_amdgcn_s_setprio(0); } while (0)
#define WAIT_LGKM0 do { asm volatile("s_waitcnt lgkmcnt(0)" ::: "memory"); \
                        __builtin_amdgcn_sched_barrier(0); } while (0)
// one K-tile: 4 phases (reads quadrant-paired; stagger slots per m201)
#define KTILE(t, AB, BB) do { \
    /* q0: b01+a03 (12 reads); stage B(t+1,h1) */ \
    RD_B2(BB, 0); RD_A4(AB, 0); \
    STAGE_B2((t) + 1, 1); \
    asm volatile("s_waitcnt lgkmcnt(8)" ::: "memory"); \
    barx(); WAIT_LGKM0; \
    MM(0, 0); \
    barx(); \
    /* q1: b23 (4 reads); no stage */ \
    RD_B2(BB, 1); \
    barx(); WAIT_LGKM0; \
    MM(0, 1); \
    barx(); \
    /* q2: a47 (8 reads); stage B(t+2,h0) */ \
    RD_A4(AB, 1); \
    STAGE_B2((t) + 2, 0); \
    barx(); WAIT_LGKM0; \
    MM(1, 1); \
    barx(); \
    /* q3: no reads; stage A(t+2,h0)+A(t+2,h1); counted vmcnt */ \
    STAGE_A2((t) + 2, 0); \
    STAGE_A2((t) + 2, 1); \
    barx(); \
    __builtin_amdgcn_sched_barrier(0); \
    MM(1, 0); \
    if ((t) + 2 < KT) asm volatile("s_waitcnt vmcnt(6)" ::: "memory"); \
    else              asm volatile("s_waitcnt vmcnt(0)" ::: "memory"); \
    barx(); } while (0)

  f32x4 acc[8][4];
#pragma unroll
  for (int m = 0; m < 8; ++m)
#pragma unroll
    for (int n = 0; n < 4; ++n) acc[m][n] = f32x4{0.f, 0.f, 0.f, 0.f};

  // ---- prologue: tile0 (4 halves) + {B(1,h0), A(1,h0), A(1,h1)} ----
  STAGE_A2(0, 0); STAGE_A2(0, 1); STAGE_B2(0, 0); STAGE_B2(0, 1);
  STAGE_B2(1, 0); STAGE_A2(1, 0); STAGE_A2(1, 1);
  asm volatile("s_waitcnt vmcnt(6)" ::: "memory");
  barx();

  for (int i = 0; i < (KT >> 1); ++i) {
    const int ta = 2 * i, tb = 2 * i + 1;
    bf16x8 a[8][2], b[4][2];
    KTILE(ta, Ab_e, Bb_e);      // even parity
    KTILE(tb, Ab_o, Bb_o);      // odd parity
  }

  // ---- epilogue ----
  const int rgrp = lane >> 4, cid = lane & 15;
  if constexpr (EPI == 1) {
#pragma unroll
    for (int m = 0; m < 8; ++m)
#pragma unroll
      for (int n = 0; n < 4; ++n)
#pragma unroll
        for (int j = 0; j < 4; ++j) {
          int row = m0 + wm + m * 16 + rgrp * 4 + j;
          int col = n0 + wn + n * 16 + cid;
          o_s[(size_t)row * ldc + col] = f2bf(acc[m][n][j] * scale);
        }
  } else {
    const int kidx  = n0 >> 10;               // 256-tile stays within one k
    const int dbase = (n0 & 1023) + wn;
#pragma unroll
    for (int m = 0; m < 8; ++m)
#pragma unroll
      for (int j = 0; j < 4; ++j) {
        int row = m0 + wm + m * 16 + rgrp * 4 + j;
        float p = 0.f;
#pragma unroll
        for (int n = 0; n < 4; ++n)
          p += acc[m][n][j] * bf2f(Hu[(size_t)row * AA + dbase + n * 16 + cid]);
        p += __shfl_xor(p, 1, 64);
        p += __shfl_xor(p, 2, 64);
        p += __shfl_xor(p, 4, 64);
        p += __shfl_xor(p, 8, 64);
        if (cid == 0) atomicAdd(&o_e[(size_t)row * KE + kidx], p);
      }
  }
#undef STAGE_A2
#undef STAGE_B2
#undef RD_A4
#undef RD_B2
#undef MM
#undef WAIT_LGKM0
#undef KTILE
}

// ---------------------------------------------------------------------------
// Generic 128x128-tile bf16 GEMM, C = A @ B^T (2-phase; QKV / PV / fallbacks)
// ---------------------------------------------------------------------------
#define BM 128
#define BN 128
#define BK 64

template<int EPI, bool BF32>
__global__ __launch_bounds__(256)
void gemm_bt(const u16* __restrict__ A, int lda,
             const void* __restrict__ Bptr, int ldb,
             int MT, int NT, int K,
             u16* __restrict__ o_q, u16* __restrict__ o_k, u16* __restrict__ o_vt,
             const float* __restrict__ biasc,
             u16* __restrict__ o_s, float scale, int ldc,
             const u16* __restrict__ Hu, float* __restrict__ o_e)
{
  const int nb  = MT * NT;
  const int per = nb >> 3;                    // grids are multiples of 8
  int bid = blockIdx.x;
  bid = (bid & 7) * per + (bid >> 3);         // XCD-contiguous chunks
  const int mt = bid % MT, nt = bid / MT;     // mt fast => B panel L2 reuse
  const int m0 = mt * BM, n0 = nt * BN;

  __shared__ u16 As[BM * BK];
  __shared__ u16 Bs[BN * BK];

  const int tid  = threadIdx.x;
  const int lane = tid & 63, wave = tid >> 6;
  const int wm = (wave >> 1) * 64, wn = (wave & 1) * 64;

  f32x4 acc[4][4];
#pragma unroll
  for (int m = 0; m < 4; ++m)
#pragma unroll
    for (int n = 0; n < 4; ++n) acc[m][n] = f32x4{0.f, 0.f, 0.f, 0.f};

  const u16*   Bh = (const u16*)Bptr;
  const float* Bf = (const float*)Bptr;

  const int KT = K / BK;
  for (int kt = 0; kt < KT; ++kt) {
    const int k0 = kt * BK;
#pragma unroll
    for (int it = 0; it < 4; ++it) {
      int o = it * 4096 + wave * 1024 + lane * 16;
      int r = o >> 7;
      int c = (o & 127) >> 1;
      gload16(A + (size_t)(m0 + r) * lda + k0 + c,
              &As[(it * 4096 + wave * 1024) >> 1]);
    }
    if constexpr (!BF32) {
#pragma unroll
      for (int it = 0; it < 4; ++it) {
        int o = it * 4096 + wave * 1024 + lane * 16;
        int r = o >> 7;
        int c = (o & 127) >> 1;
        gload16(Bh + (size_t)(n0 + r) * ldb + k0 + c,
                &Bs[(it * 4096 + wave * 1024) >> 1]);
      }
    } else {
#pragma unroll
      for (int it = 0; it < 8; ++it) {
        int e = it * 1024 + tid * 4;
        int r = e >> 6, c = e & 63;
        const float4 v = *(const float4*)(Bf + (size_t)(n0 + r) * ldb + k0 + c);
        ushort4 h;
        h.x = f2bf(v.x); h.y = f2bf(v.y); h.z = f2bf(v.z); h.w = f2bf(v.w);
        *(ushort4*)&Bs[r * BK + c] = h;
      }
    }
    asm volatile("s_waitcnt vmcnt(0)" ::: "memory");
    __syncthreads();

#pragma unroll
    for (int kk = 0; kk < 2; ++kk) {
      const int ro = lane & 15;
      const int ko = kk * 32 + (lane >> 4) * 8;
      bf16x8 af[4], bfg[4];
#pragma unroll
      for (int m = 0; m < 4; ++m)
        af[m] = *(const bf16x8*)&As[(wm + m * 16 + ro) * BK + ko];
#pragma unroll
      for (int n = 0; n < 4; ++n)
        bfg[n] = *(const bf16x8*)&Bs[(wn + n * 16 + ro) * BK + ko];
#pragma unroll
      for (int m = 0; m < 4; ++m)
#pragma unroll
        for (int n = 0; n < 4; ++n)
          acc[m][n] = __builtin_amdgcn_mfma_f32_16x16x32_bf16(
              af[m], bfg[n], acc[m][n], 0, 0, 0);
    }
    __syncthreads();
  }

  const int rgrp = lane >> 4, cid = lane & 15;

  if constexpr (EPI == 0) {
#pragma unroll
    for (int m = 0; m < 4; ++m)
#pragma unroll
      for (int n = 0; n < 4; ++n)
#pragma unroll
        for (int j = 0; j < 4; ++j) {
          int row = m0 + wm + m * 16 + rgrp * 4 + j;
          int col = n0 + wn + n * 16 + cid;
          float v = acc[m][n][j] + biasc[col];
          u16 h = f2bf(v);
          if (col < 1024)       o_q[(size_t)row * AA + col] = h;
          else if (col < 2048)  o_k[(size_t)row * AA + (col - 1024)] = h;
          else                  o_vt[(size_t)(col - 2048) * NTOK + row] = h;
        }
  } else if constexpr (EPI == 1) {
#pragma unroll
    for (int m = 0; m < 4; ++m)
#pragma unroll
      for (int n = 0; n < 4; ++n)
#pragma unroll
        for (int j = 0; j < 4; ++j) {
          int row = m0 + wm + m * 16 + rgrp * 4 + j;
          int col = n0 + wn + n * 16 + cid;
          o_s[(size_t)row * ldc + col] = f2bf(acc[m][n][j] * scale);
        }
  } else {
    const int kidx  = n0 >> 10;
    const int dbase = (n0 & 1023) + wn;
#pragma unroll
    for (int m = 0; m < 4; ++m)
#pragma unroll
      for (int j = 0; j < 4; ++j) {
        int row = m0 + wm + m * 16 + rgrp * 4 + j;
        float p = 0.f;
#pragma unroll
        for (int n = 0; n < 4; ++n) {
          int d = dbase + n * 16 + cid;
          p += acc[m][n][j] * bf2f(Hu[(size_t)row * AA + d]);
        }
        p += __shfl_xor(p, 1, 64);
        p += __shfl_xor(p, 2, 64);
        p += __shfl_xor(p, 4, 64);
        p += __shfl_xor(p, 8, 64);
        if (cid == 0) atomicAdd(&o_e[(size_t)row * KE + kidx], p);
      }
  }
}

// ---------------------------------------------------------------------------
// Row softmax over 8192 bf16 columns, in place. One block per row.
// ---------------------------------------------------------------------------
__global__ __launch_bounds__(256)
void softmax_rows(u16* __restrict__ S)
{
  const size_t base = (size_t)blockIdx.x * 8192;
  const int tid = threadIdx.x;
  const int lane = tid & 63, wave = tid >> 6;
  float v[32];
#pragma unroll
  for (int c = 0; c < 4; ++c) {
    u16x8 u = *(const u16x8*)&S[base + c * 2048 + tid * 8];
#pragma unroll
    for (int j = 0; j < 8; ++j) v[c * 8 + j] = bf2f(u[j]);
  }
  float mx = -1e30f;
#pragma unroll
  for (int i = 0; i < 32; ++i) mx = fmaxf(mx, v[i]);
#pragma unroll
  for (int off = 1; off < 64; off <<= 1) mx = fmaxf(mx, __shfl_xor(mx, off, 64));
  __shared__ float r1[4], r2[4];
  if (lane == 0) r1[wave] = mx;
  __syncthreads();
  mx = fmaxf(fmaxf(r1[0], r1[1]), fmaxf(r1[2], r1[3]));

  float s = 0.f;
#pragma unroll
  for (int i = 0; i < 32; ++i) { v[i] = __expf(v[i] - mx); s += v[i]; }
#pragma unroll
  for (int off = 1; off < 64; off <<= 1) s += __shfl_xor(s, off, 64);
  if (lane == 0) r2[wave] = s;
  __syncthreads();
  s = r2[0] + r2[1] + r2[2] + r2[3];
  const float inv = 1.f / s;
#pragma unroll
  for (int c = 0; c < 4; ++c) {
    u16x8 u;
#pragma unroll
    for (int j = 0; j < 8; ++j) u[j] = f2bf(v[c * 8 + j] * inv);
    *(u16x8*)&S[base + c * 2048 + tid * 8] = u;
  }
}

// ---------------------------------------------------------------------------
// Gather Hu/Hv rows from attn_emb. Handles data delivered as int64 OR int32.
// ---------------------------------------------------------------------------
__global__ __launch_bounds__(256)
void gather_rows(const unsigned* __restrict__ dw, const u16* __restrict__ AE,
                 u16* __restrict__ Hu, u16* __restrict__ Hv)
{
  bool i64 = true;
#pragma unroll
  for (int w = 1; w < 32; w += 2) i64 = i64 && (dw[w] == 0u);
  const int e = blockIdx.x;
  const unsigned iu = i64 ? dw[4 * e]     : dw[2 * e];
  const unsigned iv = i64 ? dw[4 * e + 2] : dw[2 * e + 1];
  const int t = threadIdx.x;
  *(ushort4*)&Hu[(size_t)e * AA + t * 4] = *(const ushort4*)&AE[(size_t)iu * AA + t * 4];
  *(ushort4*)&Hv[(size_t)e * AA + t * 4] = *(const ushort4*)&AE[(size_t)iv * AA + t * 4];
}

// zero d_out + build concatenated bias
__global__ __launch_bounds__(256)
void init_misc(float* __restrict__ out_e, const float* __restrict__ bq,
               const float* __restrict__ bk, const float* __restrict__ bv,
               float* __restrict__ biasc)
{
  const int i = blockIdx.x * 256 + threadIdx.x;
  if (i < EE * KE) out_e[i] = 0.f;
  if (i < 1024) {
    biasc[i]        = bq[i];
    biasc[1024 + i] = bk[i];
    biasc[2048 + i] = bv[i];
  }
}

// grid-stride f32 -> bf16 conversion, float4 granularity
__global__ __launch_bounds__(256)
void cvt_f32_bf16_v4(const float* __restrict__ src, u16* __restrict__ dst, int n4)
{
  for (int i = blockIdx.x * 256 + threadIdx.x; i < n4; i += gridDim.x * 256) {
    float4 v = ((const float4*)src)[i];
    ushort4 h; h.x = f2bf(v.x); h.y = f2bf(v.y); h.z = f2bf(v.z); h.w = f2bf(v.w);
    ((ushort4*)dst)[i] = h;
  }
}

// WqkvT[n][d] = W*(d, n&1023) for n in [0,3072)
__global__ __launch_bounds__(256)
void build_wT(const float* __restrict__ Wq, const float* __restrict__ Wk,
              const float* __restrict__ Wv, u16* __restrict__ WT)
{
  const int nn = blockIdx.x;    // 0..3071
  const int d  = threadIdx.x;   // 0..255
  const float* W = (nn < 1024) ? Wq : ((nn < 2048) ? Wk : Wv);
  WT[nn * DIM + d] = f2bf(W[(size_t)d * AA + (nn & 1023)]);
}

// ---------------------------------------------------------------------------
extern "C" void kernel_launch(void* const* d_in, const int* in_sizes, int n_in,
                              void* d_out, int out_size, void* d_ws, size_t ws_size,
                              hipStream_t stream)
{
  (void)in_sizes; (void)out_size;
  if (n_in < 9) return;
  const float*    emb  = (const float*)d_in[0];
  const unsigned* data = (const unsigned*)d_in[1];
  const float* Wq = (const float*)d_in[2];
  const float* bq = (const float*)d_in[3];
  const float* Wk = (const float*)d_in[4];
  const float* bk = (const float*)d_in[5];
  const float* Wv = (const float*)d_in[6];
  const float* bv = (const float*)d_in[7];
  const float* We = (const float*)d_in[8];
  float* out = (float*)d_out;

  char* ws = (char*)d_ws;
  size_t off = 0;
  auto alloc = [&](size_t bytes) -> void* {
    void* p = ws + off;
    off += (bytes + 255) & ~(size_t)255;
    return p;
  };
  u16*   emb_b = (u16*)alloc((size_t)NTOK * DIM * 2);     //  4.2 MB
  u16*   WT    = (u16*)alloc((size_t)3072 * DIM * 2);     //  1.6 MB
  float* biasc = (float*)alloc(3072 * 4);
  u16*   Qb    = (u16*)alloc((size_t)NTOK * AA * 2);      // 16.8 MB
  u16*   Kb    = (u16*)alloc((size_t)NTOK * AA * 2);
  u16*   Vt    = (u16*)alloc((size_t)AA * NTOK * 2);
  u16*   AE    = (u16*)alloc((size_t)NTOK * AA * 2);
  u16*   Hu    = (u16*)alloc((size_t)EE * AA * 2);        //  8.4 MB
  u16*   Hv    = (u16*)alloc((size_t)EE * AA * 2);

  // bf16 copy of W_edge (136 MB) if it fits alongside a score chunk
  const size_t webf_bytes = ((size_t)KE * AA * AA * 2 + 255) & ~(size_t)255;
  u16* We_b = nullptr;
  if (off + webf_bytes + (size_t)1024 * NTOK * 2 <= ws_size) {
    We_b = (u16*)(ws + off);
    off += webf_bytes;
  }

  int chunk = 4096;  // Sc = 64 MB stays L3-resident for softmax + PV
  while (chunk > 128 && off + (size_t)chunk * NTOK * 2 > ws_size) chunk >>= 1;
  u16* Sc = (u16*)alloc((size_t)chunk * NTOK * 2);
  if (off > ws_size) {
    fprintf(stderr, "kernel_launch: ws too small (need %zu, have %zu)\n", off, ws_size);
    return;
  }

  init_misc<<<(EE * KE) / 256, 256, 0, stream>>>(out, bq, bk, bv, biasc);
  cvt_f32_bf16_v4<<<2048, 256, 0, stream>>>(emb, emb_b, NTOK * DIM / 4);
  build_wT<<<3072, 256, 0, stream>>>(Wq, Wk, Wv, WT);
  if (We_b)
    cvt_f32_bf16_v4<<<4096, 256, 0, stream>>>(We, We_b, KE * AA * AA / 4);

  // QKV: (8192,3072,256) on the 128^2 kernel (K too small for the pipeline)
  gemm_bt<0, false><<<64 * 24, 256, 0, stream>>>(
      emb_b, DIM, WT, DIM, 64, 24, DIM,
      Qb, Kb, Vt, biasc, nullptr, 0.f, 0, nullptr, nullptr);

  // attention, Q-chunked
  const int nch = NTOK / chunk;
  for (int ci = 0; ci < nch; ++ci) {
    const u16* Qc = Qb + (size_t)ci * chunk * AA;
    const bool big = ((chunk & 2047) == 0);
    if (big)
      gemm8s<1><<<(chunk / 256) * 32, 512, 0, stream>>>(
          Qc, AA, Kb, AA, chunk / 256, 32, AA,
          Sc, 0.0625f, NTOK, nullptr, nullptr);
    else
      gemm_bt<1, false><<<(chunk / 128) * 64, 256, 0, stream>>>(
          Qc, AA, Kb, AA, chunk / 128, 64, AA,
          nullptr, nullptr, nullptr, nullptr, Sc, 0.0625f, NTOK, nullptr, nullptr);
    softmax_rows<<<chunk, 256, 0, stream>>>(Sc);
    // PV on the 128^2 kernel: (chunk/128)*8 = 256 blocks = full machine
    gemm_bt<1, false><<<(chunk / 128) * 8, 256, 0, stream>>>(
        Sc, NTOK, Vt, NTOK, chunk / 128, 8, NTOK,
        nullptr, nullptr, nullptr, nullptr,
        AE + (size_t)ci * chunk * AA, 1.0f, AA, nullptr, nullptr);
  }

  gather_rows<<<EE, 256, 0, stream>>>(data, AE, Hu, Hv);

  // edge bilinear: non-persistent 8-phase, grid 16x260 = 4160 blocks
  if (We_b)
    gemm8s<2><<<16 * 260, 512, 0, stream>>>(
        Hv, AA, We_b, AA, 16, 260, AA,
        nullptr, 0.f, 0, Hu, out);
  else
    gemm_bt<3, true><<<32 * 520, 256, 0, stream>>>(
        Hv, AA, We, AA, 32, 520, AA,
        nullptr, nullptr, nullptr, nullptr, nullptr, 0.f, 0, Hu, out);
}